// Round 9
// baseline (391.264 us; speedup 1.0000x reference)
//
#include <hip/hip_runtime.h>

// ---- bf16 helpers (manual, finite-value RNE) ----
static __device__ __forceinline__ unsigned short f2bf(float f) {
    unsigned u = __float_as_uint(f);
    unsigned r = (u + 0x7FFF + ((u >> 16) & 1)) >> 16;
    return (unsigned short)r;
}
static __device__ __forceinline__ float bf2f(unsigned short h) {
    return __uint_as_float(((unsigned)h) << 16);
}

// ==================== bucket binning ====================
#define BKT_SHIFT 7
#define BKT_NODES 128
#define CHUNK 32768  // edges per hist/scatter block (512 thr x 64)

__global__ __launch_bounds__(512) void hist_k(const int* __restrict__ dst, int* __restrict__ histG,
                                              int B, int NB, int E) {
    __shared__ int hist[1024];
    int tid = threadIdx.x;
    for (int i = tid; i < NB; i += 512) hist[i] = 0;
    __syncthreads();
    int base = blockIdx.x * CHUNK;
    for (int i = tid; i < CHUNK; i += 512) {
        int e = base + i;
        if (e >= E) break;
        atomicAdd(&hist[dst[e] >> BKT_SHIFT], 1);
    }
    __syncthreads();
    for (int i = tid; i < NB; i += 512) histG[(size_t)i * B + blockIdx.x] = hist[i];
}

__global__ __launch_bounds__(512) void scatter_k(const int* __restrict__ src, const int* __restrict__ dst,
                                                 const int* __restrict__ scanG, int* __restrict__ pairs,
                                                 int B, int NB, int E) {
    __shared__ int sbase[1024];
    __shared__ int scnt[1024];
    int tid = threadIdx.x;
    for (int i = tid; i < NB; i += 512) {
        sbase[i] = scanG[(size_t)i * B + blockIdx.x];
        scnt[i] = 0;
    }
    __syncthreads();
    int base = blockIdx.x * CHUNK;
    for (int i = tid; i < CHUNK; i += 512) {
        int e = base + i;
        if (e >= E) break;
        int d = dst[e], s = src[e];
        int b = d >> BKT_SHIFT;
        int r = atomicAdd(&scnt[b], 1);
        pairs[sbase[b] + r] = (s << BKT_SHIFT) | (d & (BKT_NODES - 1));
    }
}

// ==================== scan (exclusive), 256 thr x 8 = 2048 elems/block ====================
#define SCAN_VPT 8
#define SCAN_ELEMS 2048

__global__ __launch_bounds__(256) void scan1(const int* __restrict__ in, int* __restrict__ out,
                                             int* __restrict__ blksum, int n) {
    __shared__ int sh[256];
    int base = blockIdx.x * SCAN_ELEMS + threadIdx.x * SCAN_VPT;
    int v[SCAN_VPT];
    int sum = 0;
    #pragma unroll
    for (int j = 0; j < SCAN_VPT; ++j) {
        v[j] = (base + j < n) ? in[base + j] : 0;
        sum += v[j];
    }
    sh[threadIdx.x] = sum;
    __syncthreads();
    for (int off = 1; off < 256; off <<= 1) {
        int t = (threadIdx.x >= off) ? sh[threadIdx.x - off] : 0;
        __syncthreads();
        sh[threadIdx.x] += t;
        __syncthreads();
    }
    if (threadIdx.x == 255) blksum[blockIdx.x] = sh[255];
    int run = sh[threadIdx.x] - sum;
    #pragma unroll
    for (int j = 0; j < SCAN_VPT; ++j) {
        if (base + j < n) out[base + j] = run;
        run += v[j];
    }
}

__global__ __launch_bounds__(256) void scan2(int* __restrict__ blksum, int nb) {
    __shared__ int sh[256];
    int t = threadIdx.x;
    int v = (t < nb) ? blksum[t] : 0;
    sh[t] = v;
    __syncthreads();
    for (int off = 1; off < 256; off <<= 1) {
        int u = (t >= off) ? sh[t - off] : 0;
        __syncthreads();
        sh[t] += u;
        __syncthreads();
    }
    if (t < nb) blksum[t] = sh[t] - v;
}

__global__ void scan3(int* __restrict__ out, const int* __restrict__ blksum, int n) {
    int i = blockIdx.x * blockDim.x + threadIdx.x;
    if (i < n) out[i] += blksum[i >> 11];
}

// ==================== within-bucket counting sort -> dst-sorted CSR + degree/dis ====================
#define SORT_CAP 8192

__global__ __launch_bounds__(512) void sort_bucket(const int* __restrict__ pairs,
        const int* __restrict__ scanG, int B, int NB,
        int* __restrict__ csr_src, int* __restrict__ node_start,
        int* __restrict__ cnt, float* __restrict__ dis, int n, int E) {
    __shared__ int keys[SORT_CAP];
    __shared__ int lcnt[BKT_NODES];
    __shared__ int lscan[BKT_NODES];
    __shared__ int lfill[BKT_NODES];
    int bkt = blockIdx.x, tid = threadIdx.x;
    int e0 = scanG[(size_t)bkt * B];
    int e1 = (bkt + 1 < NB) ? scanG[(size_t)(bkt + 1) * B] : E;
    int m = e1 - e0;
    if (tid < BKT_NODES) { lcnt[tid] = 0; lfill[tid] = 0; }
    __syncthreads();
    for (int i = tid; i < m; i += 512) {
        int k = pairs[e0 + i];
        if (i < SORT_CAP) keys[i] = k;
        atomicAdd(&lcnt[k & (BKT_NODES - 1)], 1);
    }
    __syncthreads();
    if (tid == 0) {
        int run = 0;
        for (int i = 0; i < BKT_NODES; ++i) { lscan[i] = run; run += lcnt[i]; }
    }
    __syncthreads();
    int nb0 = bkt << BKT_SHIFT;
    if (tid < BKT_NODES && nb0 + tid < n) {
        int deg = lcnt[tid];
        node_start[nb0 + tid] = e0 + lscan[tid];
        cnt[nb0 + tid] = deg;
        dis[nb0 + tid] = rsqrtf((float)deg + 1.0f);
    }
    for (int i = tid; i < m; i += 512) {
        int k = (i < SORT_CAP) ? keys[i] : pairs[e0 + i];
        int d = k & (BKT_NODES - 1);
        int pos = lscan[d] + atomicAdd(&lfill[d], 1);
        csr_src[e0 + pos] = k >> BKT_SHIFT;
    }
}

// ==================== gemm1: 512->32, scalar-W inner loop, bf16 out ====================
// W[k][c] addresses are thread-invariant -> compiler emits s_load; inner loop is
// v_fmac(vgpr_x, sgpr_w) with one LDS read per k. No W staging in LDS.

__global__ __launch_bounds__(128) void gemm1(const float* __restrict__ x, const float* __restrict__ W,
                                             const float* __restrict__ dis, unsigned short* __restrict__ g, int n) {
    __shared__ float xs[128][33];
    int tid = threadIdx.x;
    int node0 = blockIdx.x * 128;
    int node = node0 + tid;
    float acc[32];
    #pragma unroll
    for (int c = 0; c < 32; ++c) acc[c] = 0.f;

    for (int k0 = 0; k0 < 512; k0 += 32) {
        __syncthreads();
        #pragma unroll
        for (int r = 0; r < 8; ++r) {
            int fi = tid + r * 128;
            int nd = fi >> 3, k4 = fi & 7;
            int gn = min(node0 + nd, n - 1);
            float4 xv = *(const float4*)(x + (size_t)gn * 512 + k0 + k4 * 4);
            xs[nd][k4 * 4 + 0] = xv.x;
            xs[nd][k4 * 4 + 1] = xv.y;
            xs[nd][k4 * 4 + 2] = xv.z;
            xs[nd][k4 * 4 + 3] = xv.w;
        }
        __syncthreads();
        const float* Wc = W + (size_t)k0 * 32;
        #pragma unroll 4
        for (int k = 0; k < 32; ++k) {
            float xv = xs[tid][k];
            #pragma unroll
            for (int c = 0; c < 32; ++c) acc[c] = fmaf(xv, Wc[k * 32 + c], acc[c]);
        }
    }
    if (node < n) {
        float dv = dis[node];
        ushort4* o4 = (ushort4*)(g + (size_t)node * 32);
        #pragma unroll
        for (int q = 0; q < 8; ++q) {
            ushort4 p;
            p.x = f2bf(acc[q * 4 + 0] * dv);
            p.y = f2bf(acc[q * 4 + 1] * dv);
            p.z = f2bf(acc[q * 4 + 2] * dv);
            p.w = f2bf(acc[q * 4 + 3] * dv);
            o4[q] = p;
        }
    }
}

// ==================== gather1: CSR gather F=32 + fused (relu -> @W2 -> *dis) -> g2 bf16 ====================
// One wave per node. After reduction every lane holds out1[node][lane&31]; the
// 32->16 projection is done in-wave: lane c=lane&15, half kh=(lane>>4)&1 sums
// 16 k's via __shfl, then xor-16 combines halves.

__global__ __launch_bounds__(256) void gather1(const int* __restrict__ csr_src,
        const int* __restrict__ start, const int* __restrict__ cnt,
        const unsigned short* __restrict__ g1, const float* __restrict__ dis,
        const float* __restrict__ b1, const float* __restrict__ W2,
        unsigned short* __restrict__ g2, int n) {
    __shared__ float w2s[32 * 16];
    for (int i = threadIdx.x; i < 512; i += 256) w2s[i] = W2[i];
    __syncthreads();
    int node = blockIdx.x * 4 + (threadIdx.x >> 6);
    if (node >= n) return;
    int lane = threadIdx.x & 63;
    int f = lane & 31;
    int j = lane >> 5;
    int i0 = start[node], i1 = i0 + cnt[node];
    float acc = 0.f;
    int i = i0 + j;
    for (; i + 6 < i1; i += 8) {
        int s1 = csr_src[i];
        int s2 = csr_src[i + 2];
        int s3 = csr_src[i + 4];
        int s4 = csr_src[i + 6];
        unsigned short v1 = g1[(size_t)s1 * 32 + f];
        unsigned short v2 = g1[(size_t)s2 * 32 + f];
        unsigned short v3 = g1[(size_t)s3 * 32 + f];
        unsigned short v4 = g1[(size_t)s4 * 32 + f];
        acc += bf2f(v1) + bf2f(v2) + bf2f(v3) + bf2f(v4);
    }
    for (; i < i1; i += 2) acc += bf2f(g1[(size_t)csr_src[i] * 32 + f]);
    acc += __shfl_xor(acc, 32);
    float dv = dis[node];
    float val = (acc + bf2f(g1[(size_t)node * 32 + f])) * dv + b1[f];
    val = fmaxf(val, 0.f);  // out1[node][f], valid on all 64 lanes
    // fused 32->16 projection
    int c = lane & 15;
    int kh = (lane >> 4) & 1;
    float p = 0.f;
    #pragma unroll
    for (int kk = 0; kk < 16; ++kk) {
        int k = kh * 16 + kk;
        float xk = __shfl(val, k);
        p = fmaf(xk, w2s[k * 16 + c], p);
    }
    p += __shfl_xor(p, 16);  // combine the two k-halves
    if (lane < 16) g2[(size_t)node * 16 + c] = f2bf(p * dv);
}

// ==================== gather2: CSR gather F=16 + fused (relu -> @W3 -> *dis) -> g3 bf16 ====================
// W3 is 16x11, staged zero-padded to 16x16. Lane c=lane&15, quarter kq=lane>>4
// sums 4 k's, xor-16/32 combine.

__global__ __launch_bounds__(256) void gather2(const int* __restrict__ csr_src,
        const int* __restrict__ start, const int* __restrict__ cnt,
        const unsigned short* __restrict__ g2, const float* __restrict__ dis,
        const float* __restrict__ b2, const float* __restrict__ W3,
        unsigned short* __restrict__ g3, int n) {
    __shared__ float w3s[16 * 16];
    if (threadIdx.x < 256) {
        int k = threadIdx.x >> 4, c = threadIdx.x & 15;
        w3s[threadIdx.x] = (c < 11) ? W3[(size_t)k * 11 + c] : 0.f;
    }
    __syncthreads();
    int node = blockIdx.x * 4 + (threadIdx.x >> 6);
    if (node >= n) return;
    int lane = threadIdx.x & 63;
    int f = lane & 15;
    int j = lane >> 4;
    int i0 = start[node], i1 = i0 + cnt[node];
    float acc = 0.f;
    int i = i0 + j;
    for (; i + 12 < i1; i += 16) {
        int s1 = csr_src[i];
        int s2 = csr_src[i + 4];
        int s3 = csr_src[i + 8];
        int s4 = csr_src[i + 12];
        unsigned short v1 = g2[(size_t)s1 * 16 + f];
        unsigned short v2 = g2[(size_t)s2 * 16 + f];
        unsigned short v3 = g2[(size_t)s3 * 16 + f];
        unsigned short v4 = g2[(size_t)s4 * 16 + f];
        acc += bf2f(v1) + bf2f(v2) + bf2f(v3) + bf2f(v4);
    }
    for (; i < i1; i += 4) acc += bf2f(g2[(size_t)csr_src[i] * 16 + f]);
    acc += __shfl_xor(acc, 16);
    acc += __shfl_xor(acc, 32);
    float dv = dis[node];
    float val = (acc + bf2f(g2[(size_t)node * 16 + f])) * dv + b2[f];
    val = fmaxf(val, 0.f);  // out2[node][f], valid on all 64 lanes
    // fused 16->16(11 padded) projection
    int c = lane & 15;
    int kq = lane >> 4;  // 0..3, each handles 4 k's
    float p = 0.f;
    #pragma unroll
    for (int kk = 0; kk < 4; ++kk) {
        int k = kq * 4 + kk;
        float xk = __shfl(val, k);
        p = fmaf(xk, w3s[k * 16 + c], p);
    }
    p += __shfl_xor(p, 16);
    p += __shfl_xor(p, 32);
    if (lane < 16) g3[(size_t)node * 16 + c] = f2bf(p * dv);
}

// ==================== gather3: F=16 gather + self + bias + log_softmax (11 classes) ====================

__global__ __launch_bounds__(256) void gather3(const int* __restrict__ csr_src,
        const int* __restrict__ start, const int* __restrict__ cnt,
        const unsigned short* __restrict__ g, const float* __restrict__ dis,
        const float* __restrict__ bias, float* __restrict__ out, int n) {
    int node = blockIdx.x * 4 + (threadIdx.x >> 6);
    if (node >= n) return;
    int lane = threadIdx.x & 63;
    int f = lane & 15;
    int j = lane >> 4;
    int i0 = start[node], i1 = i0 + cnt[node];
    float acc = 0.f;
    int i = i0 + j;
    for (; i + 12 < i1; i += 16) {
        int s1 = csr_src[i];
        int s2 = csr_src[i + 4];
        int s3 = csr_src[i + 8];
        int s4 = csr_src[i + 12];
        unsigned short v1 = g[(size_t)s1 * 16 + f];
        unsigned short v2 = g[(size_t)s2 * 16 + f];
        unsigned short v3 = g[(size_t)s3 * 16 + f];
        unsigned short v4 = g[(size_t)s4 * 16 + f];
        acc += bf2f(v1) + bf2f(v2) + bf2f(v3) + bf2f(v4);
    }
    for (; i < i1; i += 4) acc += bf2f(g[(size_t)csr_src[i] * 16 + f]);
    acc += __shfl_xor(acc, 16);
    acc += __shfl_xor(acc, 32);
    float val = (acc + bf2f(g[(size_t)node * 16 + f])) * dis[node] + ((f < 11) ? bias[f] : 0.f);
    float vm = (f < 11) ? val : -3.0e38f;
    #pragma unroll
    for (int m = 1; m < 16; m <<= 1) vm = fmaxf(vm, __shfl_xor(vm, m));
    float ex = (f < 11) ? __expf(val - vm) : 0.f;
    float sum = ex;
    #pragma unroll
    for (int m = 1; m < 16; m <<= 1) sum += __shfl_xor(sum, m);
    if (lane < 11) out[(size_t)node * 11 + f] = val - (__logf(sum) + vm);
}

// ==================== launch ====================

extern "C" void kernel_launch(void* const* d_in, const int* in_sizes, int n_in,
                              void* d_out, int out_size, void* d_ws, size_t ws_size,
                              hipStream_t stream) {
    const float* x  = (const float*)d_in[0];
    const int*   ei = (const int*)d_in[1];
    const float* W1 = (const float*)d_in[2];
    const float* b1 = (const float*)d_in[3];
    const float* W2 = (const float*)d_in[4];
    const float* b2 = (const float*)d_in[5];
    const float* W3 = (const float*)d_in[6];
    const float* b3 = (const float*)d_in[7];
    float* out = (float*)d_out;

    const int n = in_sizes[0] / 512;
    const int E = in_sizes[1] / 2;
    const int* src = ei;
    const int* dst = ei + E;

    const int NB = (n + BKT_NODES - 1) >> BKT_SHIFT;      // 782
    const int B  = (E + CHUNK - 1) / CHUNK;               // 98
    const int NBB = NB * B;
    const int nb_scan = (NBB + SCAN_ELEMS - 1) / SCAN_ELEMS;

    // workspace layout (4B elements)
    int* ws0 = (int*)d_ws;
    size_t off = 0;
    int*   cnt     = ws0 + off; off += (size_t)n;
    float* dis     = (float*)(ws0 + off); off += (size_t)n;
    int*   nstart  = ws0 + off; off += (size_t)n;
    int*   scanG   = ws0 + off; off += (size_t)NBB;
    int*   blksum  = ws0 + off; off += 256;
    int*   pairs   = ws0 + off; off += (size_t)E;
    int*   csr_src = ws0 + off; off += (size_t)E;
    unsigned short* g1 = (unsigned short*)(ws0 + off); off += (size_t)n * 16;  // n*32 bf16
    unsigned short* g2 = (unsigned short*)(ws0 + off); off += (size_t)n * 8;   // n*16 bf16
    unsigned short* g3 = (unsigned short*)(ws0 + off); off += (size_t)n * 8;   // n*16 bf16
    int*   histG   = (int*)g1;  // alias: histG (0.3 MB) dead before gemm1 writes g1

    // ---- bucket binning + within-bucket counting sort -> dst-sorted CSR + deg/dis ----
    hist_k<<<B, 512, 0, stream>>>(dst, histG, B, NB, E);
    scan1<<<nb_scan, 256, 0, stream>>>(histG, scanG, blksum, NBB);
    scan2<<<1, 256, 0, stream>>>(blksum, nb_scan);
    scan3<<<(NBB + 255) / 256, 256, 0, stream>>>(scanG, blksum, NBB);
    scatter_k<<<B, 512, 0, stream>>>(src, dst, scanG, pairs, B, NB, E);
    sort_bucket<<<NB, 512, 0, stream>>>(pairs, scanG, B, NB, csr_src, nstart, cnt, dis, n, E);

    // ---- layer 1 GEMM, then fused gather chains ----
    gemm1<<<(n + 127) / 128, 128, 0, stream>>>(x, W1, dis, g1, n);
    gather1<<<(n + 3) / 4, 256, 0, stream>>>(csr_src, nstart, cnt, g1, dis, b1, W2, g2, n);
    gather2<<<(n + 3) / 4, 256, 0, stream>>>(csr_src, nstart, cnt, g2, dis, b2, W3, g3, n);
    gather3<<<(n + 3) / 4, 256, 0, stream>>>(csr_src, nstart, cnt, g3, dis, b3, out, n);
}

// Round 10
// 383.579 us; speedup vs baseline: 1.0200x; 1.0200x over previous
//
#include <hip/hip_runtime.h>

// ---- bf16 helpers (manual, finite-value RNE) ----
static __device__ __forceinline__ unsigned short f2bf(float f) {
    unsigned u = __float_as_uint(f);
    unsigned r = (u + 0x7FFF + ((u >> 16) & 1)) >> 16;
    return (unsigned short)r;
}
static __device__ __forceinline__ float bf2f(unsigned short h) {
    return __uint_as_float(((unsigned)h) << 16);
}

// ==================== bucket binning ====================
#define BKT_SHIFT 7
#define BKT_NODES 128
#define CHUNK 32768  // edges per hist/scatter block (512 thr x 64)

__global__ __launch_bounds__(512) void hist_k(const int* __restrict__ dst, int* __restrict__ histG,
                                              int B, int NB, int E) {
    __shared__ int hist[1024];
    int tid = threadIdx.x;
    for (int i = tid; i < NB; i += 512) hist[i] = 0;
    __syncthreads();
    int base = blockIdx.x * CHUNK;
    for (int i = tid; i < CHUNK; i += 512) {
        int e = base + i;
        if (e >= E) break;
        atomicAdd(&hist[dst[e] >> BKT_SHIFT], 1);
    }
    __syncthreads();
    for (int i = tid; i < NB; i += 512) histG[(size_t)i * B + blockIdx.x] = hist[i];
}

__global__ __launch_bounds__(512) void scatter_k(const int* __restrict__ src, const int* __restrict__ dst,
                                                 const int* __restrict__ scanG, int* __restrict__ pairs,
                                                 int B, int NB, int E) {
    __shared__ int sbase[1024];
    __shared__ int scnt[1024];
    int tid = threadIdx.x;
    for (int i = tid; i < NB; i += 512) {
        sbase[i] = scanG[(size_t)i * B + blockIdx.x];
        scnt[i] = 0;
    }
    __syncthreads();
    int base = blockIdx.x * CHUNK;
    for (int i = tid; i < CHUNK; i += 512) {
        int e = base + i;
        if (e >= E) break;
        int d = dst[e], s = src[e];
        int b = d >> BKT_SHIFT;
        int r = atomicAdd(&scnt[b], 1);
        pairs[sbase[b] + r] = (s << BKT_SHIFT) | (d & (BKT_NODES - 1));
    }
}

// ==================== scan (exclusive), 256 thr x 8 = 2048 elems/block ====================
#define SCAN_VPT 8
#define SCAN_ELEMS 2048

__global__ __launch_bounds__(256) void scan1(const int* __restrict__ in, int* __restrict__ out,
                                             int* __restrict__ blksum, int n) {
    __shared__ int sh[256];
    int base = blockIdx.x * SCAN_ELEMS + threadIdx.x * SCAN_VPT;
    int v[SCAN_VPT];
    int sum = 0;
    #pragma unroll
    for (int j = 0; j < SCAN_VPT; ++j) {
        v[j] = (base + j < n) ? in[base + j] : 0;
        sum += v[j];
    }
    sh[threadIdx.x] = sum;
    __syncthreads();
    for (int off = 1; off < 256; off <<= 1) {
        int t = (threadIdx.x >= off) ? sh[threadIdx.x - off] : 0;
        __syncthreads();
        sh[threadIdx.x] += t;
        __syncthreads();
    }
    if (threadIdx.x == 255) blksum[blockIdx.x] = sh[255];
    int run = sh[threadIdx.x] - sum;
    #pragma unroll
    for (int j = 0; j < SCAN_VPT; ++j) {
        if (base + j < n) out[base + j] = run;
        run += v[j];
    }
}

__global__ __launch_bounds__(256) void scan2(int* __restrict__ blksum, int nb) {
    __shared__ int sh[256];
    int t = threadIdx.x;
    int v = (t < nb) ? blksum[t] : 0;
    sh[t] = v;
    __syncthreads();
    for (int off = 1; off < 256; off <<= 1) {
        int u = (t >= off) ? sh[t - off] : 0;
        __syncthreads();
        sh[t] += u;
        __syncthreads();
    }
    if (t < nb) blksum[t] = sh[t] - v;
}

__global__ void scan3(int* __restrict__ out, const int* __restrict__ blksum, int n) {
    int i = blockIdx.x * blockDim.x + threadIdx.x;
    if (i < n) out[i] += blksum[i >> 11];
}

// ==================== within-bucket counting sort -> dst-sorted CSR + degree/dis ====================
#define SORT_CAP 8192

__global__ __launch_bounds__(512) void sort_bucket(const int* __restrict__ pairs,
        const int* __restrict__ scanG, int B, int NB,
        int* __restrict__ csr_src, int* __restrict__ node_start,
        int* __restrict__ cnt, float* __restrict__ dis, int n, int E) {
    __shared__ int keys[SORT_CAP];
    __shared__ int lcnt[BKT_NODES];
    __shared__ int lscan[BKT_NODES];
    __shared__ int lfill[BKT_NODES];
    int bkt = blockIdx.x, tid = threadIdx.x;
    int e0 = scanG[(size_t)bkt * B];
    int e1 = (bkt + 1 < NB) ? scanG[(size_t)(bkt + 1) * B] : E;
    int m = e1 - e0;
    if (tid < BKT_NODES) { lcnt[tid] = 0; lfill[tid] = 0; }
    __syncthreads();
    for (int i = tid; i < m; i += 512) {
        int k = pairs[e0 + i];
        if (i < SORT_CAP) keys[i] = k;
        atomicAdd(&lcnt[k & (BKT_NODES - 1)], 1);
    }
    __syncthreads();
    if (tid == 0) {
        int run = 0;
        for (int i = 0; i < BKT_NODES; ++i) { lscan[i] = run; run += lcnt[i]; }
    }
    __syncthreads();
    int nb0 = bkt << BKT_SHIFT;
    if (tid < BKT_NODES && nb0 + tid < n) {
        int deg = lcnt[tid];
        node_start[nb0 + tid] = e0 + lscan[tid];
        cnt[nb0 + tid] = deg;
        dis[nb0 + tid] = rsqrtf((float)deg + 1.0f);
    }
    for (int i = tid; i < m; i += 512) {
        int k = (i < SORT_CAP) ? keys[i] : pairs[e0 + i];
        int d = k & (BKT_NODES - 1);
        int pos = lscan[d] + atomicAdd(&lfill[d], 1);
        csr_src[e0 + pos] = k >> BKT_SHIFT;
    }
}

// ==================== gemm1: 512->32, LDS-staged W chunks + LDS x, bf16 out ====================
// ws[k*32+c] reads are wave-broadcast (conflict-free); the fully-unrolled c loop
// vectorizes to ds_read_b128. xs stride 33 is conflict-free.

__global__ __launch_bounds__(128) void gemm1(const float* __restrict__ x, const float* __restrict__ W,
                                             const float* __restrict__ dis, unsigned short* __restrict__ g, int n) {
    __shared__ float ws[32 * 32];
    __shared__ float xs[128][33];
    int tid = threadIdx.x;
    int node0 = blockIdx.x * 128;
    int node = node0 + tid;
    float acc[32];
    #pragma unroll
    for (int c = 0; c < 32; ++c) acc[c] = 0.f;

    for (int k0 = 0; k0 < 512; k0 += 32) {
        __syncthreads();
        #pragma unroll
        for (int r = 0; r < 2; ++r) {
            int fi = tid + r * 128;
            int k = fi >> 3, c4 = fi & 7;
            *((float4*)(ws + k * 32 + c4 * 4)) = *(const float4*)(W + (size_t)(k0 + k) * 32 + c4 * 4);
        }
        #pragma unroll
        for (int r = 0; r < 8; ++r) {
            int fi = tid + r * 128;
            int nd = fi >> 3, k4 = fi & 7;
            int gn = min(node0 + nd, n - 1);
            float4 xv = *(const float4*)(x + (size_t)gn * 512 + k0 + k4 * 4);
            xs[nd][k4 * 4 + 0] = xv.x;
            xs[nd][k4 * 4 + 1] = xv.y;
            xs[nd][k4 * 4 + 2] = xv.z;
            xs[nd][k4 * 4 + 3] = xv.w;
        }
        __syncthreads();
        #pragma unroll
        for (int k = 0; k < 32; ++k) {
            float xv = xs[tid][k];
            #pragma unroll
            for (int c = 0; c < 32; ++c) acc[c] = fmaf(xv, ws[k * 32 + c], acc[c]);
        }
    }
    if (node < n) {
        float dv = dis[node];
        ushort4* o4 = (ushort4*)(g + (size_t)node * 32);
        #pragma unroll
        for (int q = 0; q < 8; ++q) {
            ushort4 p;
            p.x = f2bf(acc[q * 4 + 0] * dv);
            p.y = f2bf(acc[q * 4 + 1] * dv);
            p.z = f2bf(acc[q * 4 + 2] * dv);
            p.w = f2bf(acc[q * 4 + 3] * dv);
            o4[q] = p;
        }
    }
}

// ==================== gather1: CSR gather F=32 + fused (relu -> @W2 -> *dis) -> g2 bf16 ====================

__global__ __launch_bounds__(256) void gather1(const int* __restrict__ csr_src,
        const int* __restrict__ start, const int* __restrict__ cnt,
        const unsigned short* __restrict__ g1, const float* __restrict__ dis,
        const float* __restrict__ b1, const float* __restrict__ W2,
        unsigned short* __restrict__ g2, int n) {
    __shared__ float w2s[32 * 16];
    for (int i = threadIdx.x; i < 512; i += 256) w2s[i] = W2[i];
    __syncthreads();
    int node = blockIdx.x * 4 + (threadIdx.x >> 6);
    if (node >= n) return;
    int lane = threadIdx.x & 63;
    int f = lane & 31;
    int j = lane >> 5;
    int i0 = start[node], i1 = i0 + cnt[node];
    float acc = 0.f;
    int i = i0 + j;
    for (; i + 6 < i1; i += 8) {
        int s1 = csr_src[i];
        int s2 = csr_src[i + 2];
        int s3 = csr_src[i + 4];
        int s4 = csr_src[i + 6];
        unsigned short v1 = g1[(size_t)s1 * 32 + f];
        unsigned short v2 = g1[(size_t)s2 * 32 + f];
        unsigned short v3 = g1[(size_t)s3 * 32 + f];
        unsigned short v4 = g1[(size_t)s4 * 32 + f];
        acc += bf2f(v1) + bf2f(v2) + bf2f(v3) + bf2f(v4);
    }
    for (; i < i1; i += 2) acc += bf2f(g1[(size_t)csr_src[i] * 32 + f]);
    acc += __shfl_xor(acc, 32);
    float dv = dis[node];
    float val = (acc + bf2f(g1[(size_t)node * 32 + f])) * dv + b1[f];
    val = fmaxf(val, 0.f);  // out1[node][f], valid on all 64 lanes
    // fused 32->16 projection
    int c = lane & 15;
    int kh = (lane >> 4) & 1;
    float p = 0.f;
    #pragma unroll
    for (int kk = 0; kk < 16; ++kk) {
        int k = kh * 16 + kk;
        float xk = __shfl(val, k);
        p = fmaf(xk, w2s[k * 16 + c], p);
    }
    p += __shfl_xor(p, 16);  // combine the two k-halves
    if (lane < 16) g2[(size_t)node * 16 + c] = f2bf(p * dv);
}

// ==================== gather2: CSR gather F=16 + fused (relu -> @W3 -> *dis) -> g3 bf16 ====================

__global__ __launch_bounds__(256) void gather2(const int* __restrict__ csr_src,
        const int* __restrict__ start, const int* __restrict__ cnt,
        const unsigned short* __restrict__ g2, const float* __restrict__ dis,
        const float* __restrict__ b2, const float* __restrict__ W3,
        unsigned short* __restrict__ g3, int n) {
    __shared__ float w3s[16 * 16];
    if (threadIdx.x < 256) {
        int k = threadIdx.x >> 4, c = threadIdx.x & 15;
        w3s[threadIdx.x] = (c < 11) ? W3[(size_t)k * 11 + c] : 0.f;
    }
    __syncthreads();
    int node = blockIdx.x * 4 + (threadIdx.x >> 6);
    if (node >= n) return;
    int lane = threadIdx.x & 63;
    int f = lane & 15;
    int j = lane >> 4;
    int i0 = start[node], i1 = i0 + cnt[node];
    float acc = 0.f;
    int i = i0 + j;
    for (; i + 12 < i1; i += 16) {
        int s1 = csr_src[i];
        int s2 = csr_src[i + 4];
        int s3 = csr_src[i + 8];
        int s4 = csr_src[i + 12];
        unsigned short v1 = g2[(size_t)s1 * 16 + f];
        unsigned short v2 = g2[(size_t)s2 * 16 + f];
        unsigned short v3 = g2[(size_t)s3 * 16 + f];
        unsigned short v4 = g2[(size_t)s4 * 16 + f];
        acc += bf2f(v1) + bf2f(v2) + bf2f(v3) + bf2f(v4);
    }
    for (; i < i1; i += 4) acc += bf2f(g2[(size_t)csr_src[i] * 16 + f]);
    acc += __shfl_xor(acc, 16);
    acc += __shfl_xor(acc, 32);
    float dv = dis[node];
    float val = (acc + bf2f(g2[(size_t)node * 16 + f])) * dv + b2[f];
    val = fmaxf(val, 0.f);  // out2[node][f], valid on all 64 lanes
    // fused 16->16(11 padded) projection
    int c = lane & 15;
    int kq = lane >> 4;  // 0..3, each handles 4 k's
    float p = 0.f;
    #pragma unroll
    for (int kk = 0; kk < 4; ++kk) {
        int k = kq * 4 + kk;
        float xk = __shfl(val, k);
        p = fmaf(xk, w3s[k * 16 + c], p);
    }
    p += __shfl_xor(p, 16);
    p += __shfl_xor(p, 32);
    if (lane < 16) g3[(size_t)node * 16 + c] = f2bf(p * dv);
}

// ==================== gather3: F=16 gather + self + bias + log_softmax (11 classes) ====================

__global__ __launch_bounds__(256) void gather3(const int* __restrict__ csr_src,
        const int* __restrict__ start, const int* __restrict__ cnt,
        const unsigned short* __restrict__ g, const float* __restrict__ dis,
        const float* __restrict__ bias, float* __restrict__ out, int n) {
    int node = blockIdx.x * 4 + (threadIdx.x >> 6);
    if (node >= n) return;
    int lane = threadIdx.x & 63;
    int f = lane & 15;
    int j = lane >> 4;
    int i0 = start[node], i1 = i0 + cnt[node];
    float acc = 0.f;
    int i = i0 + j;
    for (; i + 12 < i1; i += 16) {
        int s1 = csr_src[i];
        int s2 = csr_src[i + 4];
        int s3 = csr_src[i + 8];
        int s4 = csr_src[i + 12];
        unsigned short v1 = g[(size_t)s1 * 16 + f];
        unsigned short v2 = g[(size_t)s2 * 16 + f];
        unsigned short v3 = g[(size_t)s3 * 16 + f];
        unsigned short v4 = g[(size_t)s4 * 16 + f];
        acc += bf2f(v1) + bf2f(v2) + bf2f(v3) + bf2f(v4);
    }
    for (; i < i1; i += 4) acc += bf2f(g[(size_t)csr_src[i] * 16 + f]);
    acc += __shfl_xor(acc, 16);
    acc += __shfl_xor(acc, 32);
    float val = (acc + bf2f(g[(size_t)node * 16 + f])) * dis[node] + ((f < 11) ? bias[f] : 0.f);
    float vm = (f < 11) ? val : -3.0e38f;
    #pragma unroll
    for (int m = 1; m < 16; m <<= 1) vm = fmaxf(vm, __shfl_xor(vm, m));
    float ex = (f < 11) ? __expf(val - vm) : 0.f;
    float sum = ex;
    #pragma unroll
    for (int m = 1; m < 16; m <<= 1) sum += __shfl_xor(sum, m);
    if (lane < 11) out[(size_t)node * 11 + f] = val - (__logf(sum) + vm);
}

// ==================== launch ====================

extern "C" void kernel_launch(void* const* d_in, const int* in_sizes, int n_in,
                              void* d_out, int out_size, void* d_ws, size_t ws_size,
                              hipStream_t stream) {
    const float* x  = (const float*)d_in[0];
    const int*   ei = (const int*)d_in[1];
    const float* W1 = (const float*)d_in[2];
    const float* b1 = (const float*)d_in[3];
    const float* W2 = (const float*)d_in[4];
    const float* b2 = (const float*)d_in[5];
    const float* W3 = (const float*)d_in[6];
    const float* b3 = (const float*)d_in[7];
    float* out = (float*)d_out;

    const int n = in_sizes[0] / 512;
    const int E = in_sizes[1] / 2;
    const int* src = ei;
    const int* dst = ei + E;

    const int NB = (n + BKT_NODES - 1) >> BKT_SHIFT;      // 782
    const int B  = (E + CHUNK - 1) / CHUNK;               // 98
    const int NBB = NB * B;
    const int nb_scan = (NBB + SCAN_ELEMS - 1) / SCAN_ELEMS;

    // workspace layout (4B elements)
    int* ws0 = (int*)d_ws;
    size_t off = 0;
    int*   cnt     = ws0 + off; off += (size_t)n;
    float* dis     = (float*)(ws0 + off); off += (size_t)n;
    int*   nstart  = ws0 + off; off += (size_t)n;
    int*   scanG   = ws0 + off; off += (size_t)NBB;
    int*   blksum  = ws0 + off; off += 256;
    int*   pairs   = ws0 + off; off += (size_t)E;
    int*   csr_src = ws0 + off; off += (size_t)E;
    unsigned short* g1 = (unsigned short*)(ws0 + off); off += (size_t)n * 16;  // n*32 bf16
    unsigned short* g2 = (unsigned short*)(ws0 + off); off += (size_t)n * 8;   // n*16 bf16
    unsigned short* g3 = (unsigned short*)(ws0 + off); off += (size_t)n * 8;   // n*16 bf16
    int*   histG   = (int*)g1;  // alias: histG (0.3 MB) dead before gemm1 writes g1

    // ---- bucket binning + within-bucket counting sort -> dst-sorted CSR + deg/dis ----
    hist_k<<<B, 512, 0, stream>>>(dst, histG, B, NB, E);
    scan1<<<nb_scan, 256, 0, stream>>>(histG, scanG, blksum, NBB);
    scan2<<<1, 256, 0, stream>>>(blksum, nb_scan);
    scan3<<<(NBB + 255) / 256, 256, 0, stream>>>(scanG, blksum, NBB);
    scatter_k<<<B, 512, 0, stream>>>(src, dst, scanG, pairs, B, NB, E);
    sort_bucket<<<NB, 512, 0, stream>>>(pairs, scanG, B, NB, csr_src, nstart, cnt, dis, n, E);

    // ---- layer 1 GEMM, then fused gather chains ----
    gemm1<<<(n + 127) / 128, 128, 0, stream>>>(x, W1, dis, g1, n);
    gather1<<<(n + 3) / 4, 256, 0, stream>>>(csr_src, nstart, cnt, g1, dis, b1, W2, g2, n);
    gather2<<<(n + 3) / 4, 256, 0, stream>>>(csr_src, nstart, cnt, g2, dis, b2, W3, g3, n);
    gather3<<<(n + 3) / 4, 256, 0, stream>>>(csr_src, nstart, cnt, g3, dis, b3, out, n);
}

// Round 11
// 380.248 us; speedup vs baseline: 1.0290x; 1.0088x over previous
//
#include <hip/hip_runtime.h>

// ---- bf16 helpers (manual, finite-value RNE) ----
static __device__ __forceinline__ unsigned short f2bf(float f) {
    unsigned u = __float_as_uint(f);
    unsigned r = (u + 0x7FFF + ((u >> 16) & 1)) >> 16;
    return (unsigned short)r;
}
static __device__ __forceinline__ float bf2f(unsigned short h) {
    return __uint_as_float(((unsigned)h) << 16);
}

// ==================== bucket binning ====================
#define BKT_SHIFT 7
#define BKT_NODES 128
#define CHUNK 32768  // edges per hist/scatter block (512 thr x 64)

__global__ __launch_bounds__(512) void hist_k(const int* __restrict__ dst, int* __restrict__ histG,
                                              int B, int NB, int E) {
    __shared__ int hist[1024];
    int tid = threadIdx.x;
    for (int i = tid; i < NB; i += 512) hist[i] = 0;
    __syncthreads();
    int base = blockIdx.x * CHUNK;
    for (int i = tid; i < CHUNK; i += 512) {
        int e = base + i;
        if (e >= E) break;
        atomicAdd(&hist[dst[e] >> BKT_SHIFT], 1);
    }
    __syncthreads();
    for (int i = tid; i < NB; i += 512) histG[(size_t)i * B + blockIdx.x] = hist[i];
}

__global__ __launch_bounds__(512) void scatter_k(const int* __restrict__ src, const int* __restrict__ dst,
                                                 const int* __restrict__ scanG, int* __restrict__ pairs,
                                                 int B, int NB, int E) {
    __shared__ int sbase[1024];
    __shared__ int scnt[1024];
    int tid = threadIdx.x;
    for (int i = tid; i < NB; i += 512) {
        sbase[i] = scanG[(size_t)i * B + blockIdx.x];
        scnt[i] = 0;
    }
    __syncthreads();
    int base = blockIdx.x * CHUNK;
    for (int i = tid; i < CHUNK; i += 512) {
        int e = base + i;
        if (e >= E) break;
        int d = dst[e], s = src[e];
        int b = d >> BKT_SHIFT;
        int r = atomicAdd(&scnt[b], 1);
        pairs[sbase[b] + r] = (s << BKT_SHIFT) | (d & (BKT_NODES - 1));
    }
}

// ==================== scan (exclusive), 256 thr x 8 = 2048 elems/block ====================
#define SCAN_VPT 8
#define SCAN_ELEMS 2048

__global__ __launch_bounds__(256) void scan1(const int* __restrict__ in, int* __restrict__ out,
                                             int* __restrict__ blksum, int n) {
    __shared__ int sh[256];
    int base = blockIdx.x * SCAN_ELEMS + threadIdx.x * SCAN_VPT;
    int v[SCAN_VPT];
    int sum = 0;
    #pragma unroll
    for (int j = 0; j < SCAN_VPT; ++j) {
        v[j] = (base + j < n) ? in[base + j] : 0;
        sum += v[j];
    }
    sh[threadIdx.x] = sum;
    __syncthreads();
    for (int off = 1; off < 256; off <<= 1) {
        int t = (threadIdx.x >= off) ? sh[threadIdx.x - off] : 0;
        __syncthreads();
        sh[threadIdx.x] += t;
        __syncthreads();
    }
    if (threadIdx.x == 255) blksum[blockIdx.x] = sh[255];
    int run = sh[threadIdx.x] - sum;
    #pragma unroll
    for (int j = 0; j < SCAN_VPT; ++j) {
        if (base + j < n) out[base + j] = run;
        run += v[j];
    }
}

__global__ __launch_bounds__(256) void scan2(int* __restrict__ blksum, int nb) {
    __shared__ int sh[256];
    int t = threadIdx.x;
    int v = (t < nb) ? blksum[t] : 0;
    sh[t] = v;
    __syncthreads();
    for (int off = 1; off < 256; off <<= 1) {
        int u = (t >= off) ? sh[t - off] : 0;
        __syncthreads();
        sh[t] += u;
        __syncthreads();
    }
    if (t < nb) blksum[t] = sh[t] - v;
}

__global__ void scan3(int* __restrict__ out, const int* __restrict__ blksum, int n) {
    int i = blockIdx.x * blockDim.x + threadIdx.x;
    if (i < n) out[i] += blksum[i >> 11];
}

// ==================== within-bucket counting sort -> dst-sorted CSR + degree/dis ====================
#define SORT_CAP 8192

__global__ __launch_bounds__(512) void sort_bucket(const int* __restrict__ pairs,
        const int* __restrict__ scanG, int B, int NB,
        int* __restrict__ csr_src, int* __restrict__ node_start,
        int* __restrict__ cnt, float* __restrict__ dis, int n, int E) {
    __shared__ int keys[SORT_CAP];
    __shared__ int lcnt[BKT_NODES];
    __shared__ int lscan[BKT_NODES];
    __shared__ int lfill[BKT_NODES];
    int bkt = blockIdx.x, tid = threadIdx.x;
    int e0 = scanG[(size_t)bkt * B];
    int e1 = (bkt + 1 < NB) ? scanG[(size_t)(bkt + 1) * B] : E;
    int m = e1 - e0;
    if (tid < BKT_NODES) { lcnt[tid] = 0; lfill[tid] = 0; }
    __syncthreads();
    for (int i = tid; i < m; i += 512) {
        int k = pairs[e0 + i];
        if (i < SORT_CAP) keys[i] = k;
        atomicAdd(&lcnt[k & (BKT_NODES - 1)], 1);
    }
    __syncthreads();
    if (tid == 0) {
        int run = 0;
        for (int i = 0; i < BKT_NODES; ++i) { lscan[i] = run; run += lcnt[i]; }
    }
    __syncthreads();
    int nb0 = bkt << BKT_SHIFT;
    if (tid < BKT_NODES && nb0 + tid < n) {
        int deg = lcnt[tid];
        node_start[nb0 + tid] = e0 + lscan[tid];
        cnt[nb0 + tid] = deg;
        dis[nb0 + tid] = rsqrtf((float)deg + 1.0f);
    }
    for (int i = tid; i < m; i += 512) {
        int k = (i < SORT_CAP) ? keys[i] : pairs[e0 + i];
        int d = k & (BKT_NODES - 1);
        int pos = lscan[d] + atomicAdd(&lfill[d], 1);
        csr_src[e0 + pos] = k >> BKT_SHIFT;
    }
}

// ==================== gemm1: 512->32, 64 nodes/block, thread=(node, col-half) ====================
// 1563 blocks x 2 waves -> ~12 waves/CU (2x the old occupancy). acc[16]/thread.
// ws reads are wave-uniform (broadcast); xs stride 33 conflict-free.

__global__ __launch_bounds__(128) void gemm1(const float* __restrict__ x, const float* __restrict__ W,
                                             const float* __restrict__ dis, unsigned short* __restrict__ g, int n) {
    __shared__ float ws[32 * 32];
    __shared__ float xs[64][33];
    int tid = threadIdx.x;
    int nd = tid & 63;
    int half = tid >> 6;              // 0 or 1: which 16 output cols
    int node0 = blockIdx.x * 64;
    int node = node0 + nd;
    float acc[16];
    #pragma unroll
    for (int c = 0; c < 16; ++c) acc[c] = 0.f;

    for (int k0 = 0; k0 < 512; k0 += 32) {
        __syncthreads();
        // W chunk: 32x32 = 256 float4, 2 per thread
        #pragma unroll
        for (int r = 0; r < 2; ++r) {
            int fi = tid + r * 128;
            int k = fi >> 3, c4 = fi & 7;
            *((float4*)(ws + k * 32 + c4 * 4)) = *(const float4*)(W + (size_t)(k0 + k) * 32 + c4 * 4);
        }
        // x chunk: 64 nodes x 32 k = 512 float4, 4 per thread (coalesced)
        #pragma unroll
        for (int r = 0; r < 4; ++r) {
            int fi = tid + r * 128;
            int xnd = fi >> 3, k4 = fi & 7;
            int gn = min(node0 + xnd, n - 1);
            float4 xv = *(const float4*)(x + (size_t)gn * 512 + k0 + k4 * 4);
            xs[xnd][k4 * 4 + 0] = xv.x;
            xs[xnd][k4 * 4 + 1] = xv.y;
            xs[xnd][k4 * 4 + 2] = xv.z;
            xs[xnd][k4 * 4 + 3] = xv.w;
        }
        __syncthreads();
        const float* wsh = ws + half * 16;
        #pragma unroll
        for (int k = 0; k < 32; ++k) {
            float xv = xs[nd][k];
            #pragma unroll
            for (int c = 0; c < 16; ++c) acc[c] = fmaf(xv, wsh[k * 32 + c], acc[c]);
        }
    }
    if (node < n) {
        float dv = dis[node];
        ushort4* o4 = (ushort4*)(g + (size_t)node * 32 + half * 16);
        #pragma unroll
        for (int q = 0; q < 4; ++q) {
            ushort4 p;
            p.x = f2bf(acc[q * 4 + 0] * dv);
            p.y = f2bf(acc[q * 4 + 1] * dv);
            p.z = f2bf(acc[q * 4 + 2] * dv);
            p.w = f2bf(acc[q * 4 + 3] * dv);
            o4[q] = p;
        }
    }
}

// ==================== gather1: CSR gather F=32 + fused (relu -> @W2 -> *dis) -> g2 bf16 ====================

__global__ __launch_bounds__(256) void gather1(const int* __restrict__ csr_src,
        const int* __restrict__ start, const int* __restrict__ cnt,
        const unsigned short* __restrict__ g1, const float* __restrict__ dis,
        const float* __restrict__ b1, const float* __restrict__ W2,
        unsigned short* __restrict__ g2, int n) {
    __shared__ float w2s[32 * 16];
    for (int i = threadIdx.x; i < 512; i += 256) w2s[i] = W2[i];
    __syncthreads();
    int node = blockIdx.x * 4 + (threadIdx.x >> 6);
    if (node >= n) return;
    int lane = threadIdx.x & 63;
    int f = lane & 31;
    int j = lane >> 5;
    int i0 = start[node], i1 = i0 + cnt[node];
    float acc = 0.f;
    int i = i0 + j;
    for (; i + 6 < i1; i += 8) {
        int s1 = csr_src[i];
        int s2 = csr_src[i + 2];
        int s3 = csr_src[i + 4];
        int s4 = csr_src[i + 6];
        unsigned short v1 = g1[(size_t)s1 * 32 + f];
        unsigned short v2 = g1[(size_t)s2 * 32 + f];
        unsigned short v3 = g1[(size_t)s3 * 32 + f];
        unsigned short v4 = g1[(size_t)s4 * 32 + f];
        acc += bf2f(v1) + bf2f(v2) + bf2f(v3) + bf2f(v4);
    }
    for (; i < i1; i += 2) acc += bf2f(g1[(size_t)csr_src[i] * 32 + f]);
    acc += __shfl_xor(acc, 32);
    float dv = dis[node];
    float val = (acc + bf2f(g1[(size_t)node * 32 + f])) * dv + b1[f];
    val = fmaxf(val, 0.f);  // out1[node][f], valid on all 64 lanes
    // fused 32->16 projection
    int c = lane & 15;
    int kh = (lane >> 4) & 1;
    float p = 0.f;
    #pragma unroll
    for (int kk = 0; kk < 16; ++kk) {
        int k = kh * 16 + kk;
        float xk = __shfl(val, k);
        p = fmaf(xk, w2s[k * 16 + c], p);
    }
    p += __shfl_xor(p, 16);  // combine the two k-halves
    if (lane < 16) g2[(size_t)node * 16 + c] = f2bf(p * dv);
}

// ==================== gather2: CSR gather F=16 + fused (relu -> @W3 -> *dis) -> g3 bf16 ====================

__global__ __launch_bounds__(256) void gather2(const int* __restrict__ csr_src,
        const int* __restrict__ start, const int* __restrict__ cnt,
        const unsigned short* __restrict__ g2, const float* __restrict__ dis,
        const float* __restrict__ b2, const float* __restrict__ W3,
        unsigned short* __restrict__ g3, int n) {
    __shared__ float w3s[16 * 16];
    if (threadIdx.x < 256) {
        int k = threadIdx.x >> 4, c = threadIdx.x & 15;
        w3s[threadIdx.x] = (c < 11) ? W3[(size_t)k * 11 + c] : 0.f;
    }
    __syncthreads();
    int node = blockIdx.x * 4 + (threadIdx.x >> 6);
    if (node >= n) return;
    int lane = threadIdx.x & 63;
    int f = lane & 15;
    int j = lane >> 4;
    int i0 = start[node], i1 = i0 + cnt[node];
    float acc = 0.f;
    int i = i0 + j;
    for (; i + 12 < i1; i += 16) {
        int s1 = csr_src[i];
        int s2 = csr_src[i + 4];
        int s3 = csr_src[i + 8];
        int s4 = csr_src[i + 12];
        unsigned short v1 = g2[(size_t)s1 * 16 + f];
        unsigned short v2 = g2[(size_t)s2 * 16 + f];
        unsigned short v3 = g2[(size_t)s3 * 16 + f];
        unsigned short v4 = g2[(size_t)s4 * 16 + f];
        acc += bf2f(v1) + bf2f(v2) + bf2f(v3) + bf2f(v4);
    }
    for (; i < i1; i += 4) acc += bf2f(g2[(size_t)csr_src[i] * 16 + f]);
    acc += __shfl_xor(acc, 16);
    acc += __shfl_xor(acc, 32);
    float dv = dis[node];
    float val = (acc + bf2f(g2[(size_t)node * 16 + f])) * dv + b2[f];
    val = fmaxf(val, 0.f);  // out2[node][f], valid on all 64 lanes
    // fused 16->16(11 padded) projection
    int c = lane & 15;
    int kq = lane >> 4;  // 0..3, each handles 4 k's
    float p = 0.f;
    #pragma unroll
    for (int kk = 0; kk < 4; ++kk) {
        int k = kq * 4 + kk;
        float xk = __shfl(val, k);
        p = fmaf(xk, w3s[k * 16 + c], p);
    }
    p += __shfl_xor(p, 16);
    p += __shfl_xor(p, 32);
    if (lane < 16) g3[(size_t)node * 16 + c] = f2bf(p * dv);
}

// ==================== gather3: F=16 gather + self + bias + log_softmax (11 classes) ====================

__global__ __launch_bounds__(256) void gather3(const int* __restrict__ csr_src,
        const int* __restrict__ start, const int* __restrict__ cnt,
        const unsigned short* __restrict__ g, const float* __restrict__ dis,
        const float* __restrict__ bias, float* __restrict__ out, int n) {
    int node = blockIdx.x * 4 + (threadIdx.x >> 6);
    if (node >= n) return;
    int lane = threadIdx.x & 63;
    int f = lane & 15;
    int j = lane >> 4;
    int i0 = start[node], i1 = i0 + cnt[node];
    float acc = 0.f;
    int i = i0 + j;
    for (; i + 12 < i1; i += 16) {
        int s1 = csr_src[i];
        int s2 = csr_src[i + 4];
        int s3 = csr_src[i + 8];
        int s4 = csr_src[i + 12];
        unsigned short v1 = g[(size_t)s1 * 16 + f];
        unsigned short v2 = g[(size_t)s2 * 16 + f];
        unsigned short v3 = g[(size_t)s3 * 16 + f];
        unsigned short v4 = g[(size_t)s4 * 16 + f];
        acc += bf2f(v1) + bf2f(v2) + bf2f(v3) + bf2f(v4);
    }
    for (; i < i1; i += 4) acc += bf2f(g[(size_t)csr_src[i] * 16 + f]);
    acc += __shfl_xor(acc, 16);
    acc += __shfl_xor(acc, 32);
    float val = (acc + bf2f(g[(size_t)node * 16 + f])) * dis[node] + ((f < 11) ? bias[f] : 0.f);
    float vm = (f < 11) ? val : -3.0e38f;
    #pragma unroll
    for (int m = 1; m < 16; m <<= 1) vm = fmaxf(vm, __shfl_xor(vm, m));
    float ex = (f < 11) ? __expf(val - vm) : 0.f;
    float sum = ex;
    #pragma unroll
    for (int m = 1; m < 16; m <<= 1) sum += __shfl_xor(sum, m);
    if (lane < 11) out[(size_t)node * 11 + f] = val - (__logf(sum) + vm);
}

// ==================== launch ====================

extern "C" void kernel_launch(void* const* d_in, const int* in_sizes, int n_in,
                              void* d_out, int out_size, void* d_ws, size_t ws_size,
                              hipStream_t stream) {
    const float* x  = (const float*)d_in[0];
    const int*   ei = (const int*)d_in[1];
    const float* W1 = (const float*)d_in[2];
    const float* b1 = (const float*)d_in[3];
    const float* W2 = (const float*)d_in[4];
    const float* b2 = (const float*)d_in[5];
    const float* W3 = (const float*)d_in[6];
    const float* b3 = (const float*)d_in[7];
    float* out = (float*)d_out;

    const int n = in_sizes[0] / 512;
    const int E = in_sizes[1] / 2;
    const int* src = ei;
    const int* dst = ei + E;

    const int NB = (n + BKT_NODES - 1) >> BKT_SHIFT;      // 782
    const int B  = (E + CHUNK - 1) / CHUNK;               // 98
    const int NBB = NB * B;
    const int nb_scan = (NBB + SCAN_ELEMS - 1) / SCAN_ELEMS;

    // workspace layout (4B elements)
    int* ws0 = (int*)d_ws;
    size_t off = 0;
    int*   cnt     = ws0 + off; off += (size_t)n;
    float* dis     = (float*)(ws0 + off); off += (size_t)n;
    int*   nstart  = ws0 + off; off += (size_t)n;
    int*   scanG   = ws0 + off; off += (size_t)NBB;
    int*   blksum  = ws0 + off; off += 256;
    int*   pairs   = ws0 + off; off += (size_t)E;
    int*   csr_src = ws0 + off; off += (size_t)E;
    unsigned short* g1 = (unsigned short*)(ws0 + off); off += (size_t)n * 16;  // n*32 bf16
    unsigned short* g2 = (unsigned short*)(ws0 + off); off += (size_t)n * 8;   // n*16 bf16
    unsigned short* g3 = (unsigned short*)(ws0 + off); off += (size_t)n * 8;   // n*16 bf16
    int*   histG   = (int*)g1;  // alias: histG (0.3 MB) dead before gemm1 writes g1

    // ---- bucket binning + within-bucket counting sort -> dst-sorted CSR + deg/dis ----
    hist_k<<<B, 512, 0, stream>>>(dst, histG, B, NB, E);
    scan1<<<nb_scan, 256, 0, stream>>>(histG, scanG, blksum, NBB);
    scan2<<<1, 256, 0, stream>>>(blksum, nb_scan);
    scan3<<<(NBB + 255) / 256, 256, 0, stream>>>(scanG, blksum, NBB);
    scatter_k<<<B, 512, 0, stream>>>(src, dst, scanG, pairs, B, NB, E);
    sort_bucket<<<NB, 512, 0, stream>>>(pairs, scanG, B, NB, csr_src, nstart, cnt, dis, n, E);

    // ---- layer 1 GEMM, then fused gather chains ----
    gemm1<<<(n + 63) / 64, 128, 0, stream>>>(x, W1, dis, g1, n);
    gather1<<<(n + 3) / 4, 256, 0, stream>>>(csr_src, nstart, cnt, g1, dis, b1, W2, g2, n);
    gather2<<<(n + 3) / 4, 256, 0, stream>>>(csr_src, nstart, cnt, g2, dis, b2, W3, g3, n);
    gather3<<<(n + 3) / 4, 256, 0, stream>>>(csr_src, nstart, cnt, g3, dis, b3, out, n);
}

// Round 12
// 342.831 us; speedup vs baseline: 1.1413x; 1.1091x over previous
//
#include <hip/hip_runtime.h>

// ---- bf16 helpers (manual, finite-value RNE) ----
static __device__ __forceinline__ unsigned short f2bf(float f) {
    unsigned u = __float_as_uint(f);
    unsigned r = (u + 0x7FFF + ((u >> 16) & 1)) >> 16;
    return (unsigned short)r;
}
static __device__ __forceinline__ float bf2f(unsigned short h) {
    return __uint_as_float(((unsigned)h) << 16);
}

typedef __attribute__((ext_vector_type(8))) short bf16x8;
typedef __attribute__((ext_vector_type(4))) float f32x4;

// ==================== bucket binning ====================
#define BKT_SHIFT 7
#define BKT_NODES 128
#define CHUNK 32768  // edges per hist/scatter block (512 thr x 64)

__global__ __launch_bounds__(512) void hist_k(const int* __restrict__ dst, int* __restrict__ histG,
                                              int B, int NB, int E) {
    __shared__ int hist[1024];
    int tid = threadIdx.x;
    for (int i = tid; i < NB; i += 512) hist[i] = 0;
    __syncthreads();
    int base = blockIdx.x * CHUNK;
    for (int i = tid; i < CHUNK; i += 512) {
        int e = base + i;
        if (e >= E) break;
        atomicAdd(&hist[dst[e] >> BKT_SHIFT], 1);
    }
    __syncthreads();
    for (int i = tid; i < NB; i += 512) histG[(size_t)i * B + blockIdx.x] = hist[i];
}

__global__ __launch_bounds__(512) void scatter_k(const int* __restrict__ src, const int* __restrict__ dst,
                                                 const int* __restrict__ scanG, int* __restrict__ pairs,
                                                 int B, int NB, int E) {
    __shared__ int sbase[1024];
    __shared__ int scnt[1024];
    int tid = threadIdx.x;
    for (int i = tid; i < NB; i += 512) {
        sbase[i] = scanG[(size_t)i * B + blockIdx.x];
        scnt[i] = 0;
    }
    __syncthreads();
    int base = blockIdx.x * CHUNK;
    for (int i = tid; i < CHUNK; i += 512) {
        int e = base + i;
        if (e >= E) break;
        int d = dst[e], s = src[e];
        int b = d >> BKT_SHIFT;
        int r = atomicAdd(&scnt[b], 1);
        pairs[sbase[b] + r] = (s << BKT_SHIFT) | (d & (BKT_NODES - 1));
    }
}

// ==================== scan (exclusive), 256 thr x 8 = 2048 elems/block ====================
#define SCAN_VPT 8
#define SCAN_ELEMS 2048

__global__ __launch_bounds__(256) void scan1(const int* __restrict__ in, int* __restrict__ out,
                                             int* __restrict__ blksum, int n) {
    __shared__ int sh[256];
    int base = blockIdx.x * SCAN_ELEMS + threadIdx.x * SCAN_VPT;
    int v[SCAN_VPT];
    int sum = 0;
    #pragma unroll
    for (int j = 0; j < SCAN_VPT; ++j) {
        v[j] = (base + j < n) ? in[base + j] : 0;
        sum += v[j];
    }
    sh[threadIdx.x] = sum;
    __syncthreads();
    for (int off = 1; off < 256; off <<= 1) {
        int t = (threadIdx.x >= off) ? sh[threadIdx.x - off] : 0;
        __syncthreads();
        sh[threadIdx.x] += t;
        __syncthreads();
    }
    if (threadIdx.x == 255) blksum[blockIdx.x] = sh[255];
    int run = sh[threadIdx.x] - sum;
    #pragma unroll
    for (int j = 0; j < SCAN_VPT; ++j) {
        if (base + j < n) out[base + j] = run;
        run += v[j];
    }
}

__global__ __launch_bounds__(256) void scan2(int* __restrict__ blksum, int nb) {
    __shared__ int sh[256];
    int t = threadIdx.x;
    int v = (t < nb) ? blksum[t] : 0;
    sh[t] = v;
    __syncthreads();
    for (int off = 1; off < 256; off <<= 1) {
        int u = (t >= off) ? sh[t - off] : 0;
        __syncthreads();
        sh[t] += u;
        __syncthreads();
    }
    if (t < nb) blksum[t] = sh[t] - v;
}

__global__ void scan3(int* __restrict__ out, const int* __restrict__ blksum, int n) {
    int i = blockIdx.x * blockDim.x + threadIdx.x;
    if (i < n) out[i] += blksum[i >> 11];
}

// ==================== within-bucket counting sort -> dst-sorted CSR + degree/dis ====================
#define SORT_CAP 8192

__global__ __launch_bounds__(512) void sort_bucket(const int* __restrict__ pairs,
        const int* __restrict__ scanG, int B, int NB,
        int* __restrict__ csr_src, int* __restrict__ node_start,
        int* __restrict__ cnt, float* __restrict__ dis, int n, int E) {
    __shared__ int keys[SORT_CAP];
    __shared__ int lcnt[BKT_NODES];
    __shared__ int lscan[BKT_NODES];
    __shared__ int lfill[BKT_NODES];
    int bkt = blockIdx.x, tid = threadIdx.x;
    int e0 = scanG[(size_t)bkt * B];
    int e1 = (bkt + 1 < NB) ? scanG[(size_t)(bkt + 1) * B] : E;
    int m = e1 - e0;
    if (tid < BKT_NODES) { lcnt[tid] = 0; lfill[tid] = 0; }
    __syncthreads();
    for (int i = tid; i < m; i += 512) {
        int k = pairs[e0 + i];
        if (i < SORT_CAP) keys[i] = k;
        atomicAdd(&lcnt[k & (BKT_NODES - 1)], 1);
    }
    __syncthreads();
    if (tid == 0) {
        int run = 0;
        for (int i = 0; i < BKT_NODES; ++i) { lscan[i] = run; run += lcnt[i]; }
    }
    __syncthreads();
    int nb0 = bkt << BKT_SHIFT;
    if (tid < BKT_NODES && nb0 + tid < n) {
        int deg = lcnt[tid];
        node_start[nb0 + tid] = e0 + lscan[tid];
        cnt[nb0 + tid] = deg;
        dis[nb0 + tid] = rsqrtf((float)deg + 1.0f);
    }
    for (int i = tid; i < m; i += 512) {
        int k = (i < SORT_CAP) ? keys[i] : pairs[e0 + i];
        int d = k & (BKT_NODES - 1);
        int pos = lscan[d] + atomicAdd(&lfill[d], 1);
        csr_src[e0 + pos] = k >> BKT_SHIFT;
    }
}

// ==================== gemm1 (MFMA): 512->32 bf16, 64 nodes/block, 4 waves ====================
// Wave w: 16 nodes x 32 cols. A = x-tile (16x32 bf16) from LDS b128 reads;
// B = W^T tile from LDS b128 reads. 32 MFMAs/wave total. Padded LDS -> 2-way banks.

__global__ __launch_bounds__(256) void gemm1_mfma(const float* __restrict__ x, const float* __restrict__ W,
                                                  const float* __restrict__ dis, unsigned short* __restrict__ g, int n) {
    __shared__ __attribute__((aligned(16))) unsigned short wT[32][520];  // [col][k], +8 pad
    __shared__ __attribute__((aligned(16))) unsigned short xb[64][72];   // [nodeLocal][k-chunk 64], +8 pad
    int tid = threadIdx.x;
    int node0 = blockIdx.x * 64;

    // one-time: stage W1 f32 -> bf16, transposed [col][k]
    #pragma unroll
    for (int r = 0; r < 16; ++r) {
        int fi = tid + r * 256;        // float4 index 0..4095
        int k = fi >> 3, c4 = (fi & 7) * 4;
        float4 wv = *(const float4*)(W + (size_t)k * 32 + c4);
        wT[c4 + 0][k] = f2bf(wv.x);
        wT[c4 + 1][k] = f2bf(wv.y);
        wT[c4 + 2][k] = f2bf(wv.z);
        wT[c4 + 3][k] = f2bf(wv.w);
    }

    int wv_ = tid >> 6;       // wave 0..3 -> node sub-tile
    int lane = tid & 63;
    int mrow = lane & 15;     // A row / B col / D col
    int kg = lane >> 4;       // k-group 0..3 (8 k each)
    f32x4 acc0 = {0.f, 0.f, 0.f, 0.f};
    f32x4 acc1 = {0.f, 0.f, 0.f, 0.f};

    for (int k0 = 0; k0 < 512; k0 += 64) {
        __syncthreads();  // xb reuse + (iter 0) W staging done
        // stage x chunk: 64 nodes x 64 k, f32 -> bf16
        #pragma unroll
        for (int r = 0; r < 4; ++r) {
            int fi = tid + r * 256;       // float4 index 0..1023
            int nd = fi >> 4, kq = (fi & 15) * 4;
            int gn = min(node0 + nd, n - 1);
            float4 xv = *(const float4*)(x + (size_t)gn * 512 + k0 + kq);
            ushort4 p;
            p.x = f2bf(xv.x); p.y = f2bf(xv.y); p.z = f2bf(xv.z); p.w = f2bf(xv.w);
            *(ushort4*)(&xb[nd][kq]) = p;
        }
        __syncthreads();
        #pragma unroll
        for (int ks = 0; ks < 2; ++ks) {
            bf16x8 a  = *(const bf16x8*)(&xb[wv_ * 16 + mrow][ks * 32 + kg * 8]);
            bf16x8 b0 = *(const bf16x8*)(&wT[mrow][k0 + ks * 32 + kg * 8]);
            bf16x8 b1 = *(const bf16x8*)(&wT[16 + mrow][k0 + ks * 32 + kg * 8]);
            acc0 = __builtin_amdgcn_mfma_f32_16x16x32_bf16(a, b0, acc0, 0, 0, 0);
            acc1 = __builtin_amdgcn_mfma_f32_16x16x32_bf16(a, b1, acc1, 0, 0, 0);
        }
    }
    // D: col = lane&15, row = (lane>>4)*4 + j
    #pragma unroll
    for (int j = 0; j < 4; ++j) {
        int node = node0 + wv_ * 16 + kg * 4 + j;
        if (node < n) {
            float dv = dis[node];
            g[(size_t)node * 32 + mrow]      = f2bf(acc0[j] * dv);
            g[(size_t)node * 32 + 16 + mrow] = f2bf(acc1[j] * dv);
        }
    }
}

// ==================== gather1: CSR gather F=32 + fused (relu -> @W2 -> *dis) -> g2 bf16 ====================

__global__ __launch_bounds__(256) void gather1(const int* __restrict__ csr_src,
        const int* __restrict__ start, const int* __restrict__ cnt,
        const unsigned short* __restrict__ g1, const float* __restrict__ dis,
        const float* __restrict__ b1, const float* __restrict__ W2,
        unsigned short* __restrict__ g2, int n) {
    __shared__ float w2s[32 * 16];
    for (int i = threadIdx.x; i < 512; i += 256) w2s[i] = W2[i];
    __syncthreads();
    int node = blockIdx.x * 4 + (threadIdx.x >> 6);
    if (node >= n) return;
    int lane = threadIdx.x & 63;
    int f = lane & 31;
    int j = lane >> 5;
    int i0 = start[node], i1 = i0 + cnt[node];
    float acc = 0.f;
    int i = i0 + j;
    for (; i + 6 < i1; i += 8) {
        int s1 = csr_src[i];
        int s2 = csr_src[i + 2];
        int s3 = csr_src[i + 4];
        int s4 = csr_src[i + 6];
        unsigned short v1 = g1[(size_t)s1 * 32 + f];
        unsigned short v2 = g1[(size_t)s2 * 32 + f];
        unsigned short v3 = g1[(size_t)s3 * 32 + f];
        unsigned short v4 = g1[(size_t)s4 * 32 + f];
        acc += bf2f(v1) + bf2f(v2) + bf2f(v3) + bf2f(v4);
    }
    for (; i < i1; i += 2) acc += bf2f(g1[(size_t)csr_src[i] * 32 + f]);
    acc += __shfl_xor(acc, 32);
    float dv = dis[node];
    float val = (acc + bf2f(g1[(size_t)node * 32 + f])) * dv + b1[f];
    val = fmaxf(val, 0.f);  // out1[node][f], valid on all 64 lanes
    // fused 32->16 projection
    int c = lane & 15;
    int kh = (lane >> 4) & 1;
    float p = 0.f;
    #pragma unroll
    for (int kk = 0; kk < 16; ++kk) {
        int k = kh * 16 + kk;
        float xk = __shfl(val, k);
        p = fmaf(xk, w2s[k * 16 + c], p);
    }
    p += __shfl_xor(p, 16);  // combine the two k-halves
    if (lane < 16) g2[(size_t)node * 16 + c] = f2bf(p * dv);
}

// ==================== gather2: CSR gather F=16 + fused (relu -> @W3 -> *dis) -> g3 bf16 ====================

__global__ __launch_bounds__(256) void gather2(const int* __restrict__ csr_src,
        const int* __restrict__ start, const int* __restrict__ cnt,
        const unsigned short* __restrict__ g2, const float* __restrict__ dis,
        const float* __restrict__ b2, const float* __restrict__ W3,
        unsigned short* __restrict__ g3, int n) {
    __shared__ float w3s[16 * 16];
    if (threadIdx.x < 256) {
        int k = threadIdx.x >> 4, c = threadIdx.x & 15;
        w3s[threadIdx.x] = (c < 11) ? W3[(size_t)k * 11 + c] : 0.f;
    }
    __syncthreads();
    int node = blockIdx.x * 4 + (threadIdx.x >> 6);
    if (node >= n) return;
    int lane = threadIdx.x & 63;
    int f = lane & 15;
    int j = lane >> 4;
    int i0 = start[node], i1 = i0 + cnt[node];
    float acc = 0.f;
    int i = i0 + j;
    for (; i + 12 < i1; i += 16) {
        int s1 = csr_src[i];
        int s2 = csr_src[i + 4];
        int s3 = csr_src[i + 8];
        int s4 = csr_src[i + 12];
        unsigned short v1 = g2[(size_t)s1 * 16 + f];
        unsigned short v2 = g2[(size_t)s2 * 16 + f];
        unsigned short v3 = g2[(size_t)s3 * 16 + f];
        unsigned short v4 = g2[(size_t)s4 * 16 + f];
        acc += bf2f(v1) + bf2f(v2) + bf2f(v3) + bf2f(v4);
    }
    for (; i < i1; i += 4) acc += bf2f(g2[(size_t)csr_src[i] * 16 + f]);
    acc += __shfl_xor(acc, 16);
    acc += __shfl_xor(acc, 32);
    float dv = dis[node];
    float val = (acc + bf2f(g2[(size_t)node * 16 + f])) * dv + b2[f];
    val = fmaxf(val, 0.f);  // out2[node][f], valid on all 64 lanes
    // fused 16->16(11 padded) projection
    int c = lane & 15;
    int kq = lane >> 4;  // 0..3, each handles 4 k's
    float p = 0.f;
    #pragma unroll
    for (int kk = 0; kk < 4; ++kk) {
        int k = kq * 4 + kk;
        float xk = __shfl(val, k);
        p = fmaf(xk, w3s[k * 16 + c], p);
    }
    p += __shfl_xor(p, 16);
    p += __shfl_xor(p, 32);
    if (lane < 16) g3[(size_t)node * 16 + c] = f2bf(p * dv);
}

// ==================== gather3: F=16 gather + self + bias + log_softmax (11 classes) ====================

__global__ __launch_bounds__(256) void gather3(const int* __restrict__ csr_src,
        const int* __restrict__ start, const int* __restrict__ cnt,
        const unsigned short* __restrict__ g, const float* __restrict__ dis,
        const float* __restrict__ bias, float* __restrict__ out, int n) {
    int node = blockIdx.x * 4 + (threadIdx.x >> 6);
    if (node >= n) return;
    int lane = threadIdx.x & 63;
    int f = lane & 15;
    int j = lane >> 4;
    int i0 = start[node], i1 = i0 + cnt[node];
    float acc = 0.f;
    int i = i0 + j;
    for (; i + 12 < i1; i += 16) {
        int s1 = csr_src[i];
        int s2 = csr_src[i + 4];
        int s3 = csr_src[i + 8];
        int s4 = csr_src[i + 12];
        unsigned short v1 = g[(size_t)s1 * 16 + f];
        unsigned short v2 = g[(size_t)s2 * 16 + f];
        unsigned short v3 = g[(size_t)s3 * 16 + f];
        unsigned short v4 = g[(size_t)s4 * 16 + f];
        acc += bf2f(v1) + bf2f(v2) + bf2f(v3) + bf2f(v4);
    }
    for (; i < i1; i += 4) acc += bf2f(g[(size_t)csr_src[i] * 16 + f]);
    acc += __shfl_xor(acc, 16);
    acc += __shfl_xor(acc, 32);
    float val = (acc + bf2f(g[(size_t)node * 16 + f])) * dis[node] + ((f < 11) ? bias[f] : 0.f);
    float vm = (f < 11) ? val : -3.0e38f;
    #pragma unroll
    for (int m = 1; m < 16; m <<= 1) vm = fmaxf(vm, __shfl_xor(vm, m));
    float ex = (f < 11) ? __expf(val - vm) : 0.f;
    float sum = ex;
    #pragma unroll
    for (int m = 1; m < 16; m <<= 1) sum += __shfl_xor(sum, m);
    if (lane < 11) out[(size_t)node * 11 + f] = val - (__logf(sum) + vm);
}

// ==================== launch ====================

extern "C" void kernel_launch(void* const* d_in, const int* in_sizes, int n_in,
                              void* d_out, int out_size, void* d_ws, size_t ws_size,
                              hipStream_t stream) {
    const float* x  = (const float*)d_in[0];
    const int*   ei = (const int*)d_in[1];
    const float* W1 = (const float*)d_in[2];
    const float* b1 = (const float*)d_in[3];
    const float* W2 = (const float*)d_in[4];
    const float* b2 = (const float*)d_in[5];
    const float* W3 = (const float*)d_in[6];
    const float* b3 = (const float*)d_in[7];
    float* out = (float*)d_out;

    const int n = in_sizes[0] / 512;
    const int E = in_sizes[1] / 2;
    const int* src = ei;
    const int* dst = ei + E;

    const int NB = (n + BKT_NODES - 1) >> BKT_SHIFT;      // 782
    const int B  = (E + CHUNK - 1) / CHUNK;               // 98
    const int NBB = NB * B;
    const int nb_scan = (NBB + SCAN_ELEMS - 1) / SCAN_ELEMS;

    // workspace layout (4B elements)
    int* ws0 = (int*)d_ws;
    size_t off = 0;
    int*   cnt     = ws0 + off; off += (size_t)n;
    float* dis     = (float*)(ws0 + off); off += (size_t)n;
    int*   nstart  = ws0 + off; off += (size_t)n;
    int*   scanG   = ws0 + off; off += (size_t)NBB;
    int*   blksum  = ws0 + off; off += 256;
    int*   pairs   = ws0 + off; off += (size_t)E;
    int*   csr_src = ws0 + off; off += (size_t)E;
    unsigned short* g1 = (unsigned short*)(ws0 + off); off += (size_t)n * 16;  // n*32 bf16
    unsigned short* g2 = (unsigned short*)(ws0 + off); off += (size_t)n * 8;   // n*16 bf16
    unsigned short* g3 = (unsigned short*)(ws0 + off); off += (size_t)n * 8;   // n*16 bf16
    int*   histG   = (int*)g1;  // alias: histG (0.3 MB) dead before gemm1 writes g1

    // ---- bucket binning + within-bucket counting sort -> dst-sorted CSR + deg/dis ----
    hist_k<<<B, 512, 0, stream>>>(dst, histG, B, NB, E);
    scan1<<<nb_scan, 256, 0, stream>>>(histG, scanG, blksum, NBB);
    scan2<<<1, 256, 0, stream>>>(blksum, nb_scan);
    scan3<<<(NBB + 255) / 256, 256, 0, stream>>>(scanG, blksum, NBB);
    scatter_k<<<B, 512, 0, stream>>>(src, dst, scanG, pairs, B, NB, E);
    sort_bucket<<<NB, 512, 0, stream>>>(pairs, scanG, B, NB, csr_src, nstart, cnt, dis, n, E);

    // ---- layer 1 GEMM (MFMA), then fused gather chains ----
    gemm1_mfma<<<(n + 63) / 64, 256, 0, stream>>>(x, W1, dis, g1, n);
    gather1<<<(n + 3) / 4, 256, 0, stream>>>(csr_src, nstart, cnt, g1, dis, b1, W2, g2, n);
    gather2<<<(n + 3) / 4, 256, 0, stream>>>(csr_src, nstart, cnt, g2, dis, b2, W3, g3, n);
    gather3<<<(n + 3) / 4, 256, 0, stream>>>(csr_src, nstart, cnt, g3, dis, b3, out, n);
}

// Round 13
// 318.840 us; speedup vs baseline: 1.2271x; 1.0752x over previous
//
#include <hip/hip_runtime.h>

// ---- bf16 helpers (manual, finite-value RNE) ----
static __device__ __forceinline__ unsigned short f2bf(float f) {
    unsigned u = __float_as_uint(f);
    unsigned r = (u + 0x7FFF + ((u >> 16) & 1)) >> 16;
    return (unsigned short)r;
}
static __device__ __forceinline__ float bf2f(unsigned short h) {
    return __uint_as_float(((unsigned)h) << 16);
}
static __device__ __forceinline__ float bflo(unsigned v) { return __uint_as_float(v << 16); }
static __device__ __forceinline__ float bfhi(unsigned v) { return __uint_as_float(v & 0xFFFF0000u); }

typedef __attribute__((ext_vector_type(8))) short bf16x8;
typedef __attribute__((ext_vector_type(8))) unsigned short u16x8;
typedef __attribute__((ext_vector_type(4))) float f32x4;

// ==================== bucket binning ====================
#define BKT_SHIFT 7
#define BKT_NODES 128
#define CHUNK 32768  // edges per hist/scatter block (512 thr x 64)

__global__ __launch_bounds__(512) void hist_k(const int* __restrict__ dst, int* __restrict__ histG,
                                              int B, int NB, int E) {
    __shared__ int hist[1024];
    int tid = threadIdx.x;
    for (int i = tid; i < NB; i += 512) hist[i] = 0;
    __syncthreads();
    int base = blockIdx.x * CHUNK;
    for (int i = tid; i < CHUNK; i += 512) {
        int e = base + i;
        if (e >= E) break;
        atomicAdd(&hist[dst[e] >> BKT_SHIFT], 1);
    }
    __syncthreads();
    for (int i = tid; i < NB; i += 512) histG[(size_t)i * B + blockIdx.x] = hist[i];
}

// scatter with scan3 folded in (adds blksum[idx>>11] on the fly)
__global__ __launch_bounds__(512) void scatter_k(const int* __restrict__ src, const int* __restrict__ dst,
                                                 const int* __restrict__ scanG, const int* __restrict__ blksum,
                                                 int* __restrict__ pairs, int B, int NB, int E) {
    __shared__ int sbase[1024];
    __shared__ int scnt[1024];
    int tid = threadIdx.x;
    for (int i = tid; i < NB; i += 512) {
        size_t idx = (size_t)i * B + blockIdx.x;
        sbase[i] = scanG[idx] + blksum[idx >> 11];
        scnt[i] = 0;
    }
    __syncthreads();
    int base = blockIdx.x * CHUNK;
    for (int i = tid; i < CHUNK; i += 512) {
        int e = base + i;
        if (e >= E) break;
        int d = dst[e], s = src[e];
        int b = d >> BKT_SHIFT;
        int r = atomicAdd(&scnt[b], 1);
        pairs[sbase[b] + r] = (s << BKT_SHIFT) | (d & (BKT_NODES - 1));
    }
}

// ==================== scan (exclusive), 256 thr x 8 = 2048 elems/block ====================
#define SCAN_VPT 8
#define SCAN_ELEMS 2048

__global__ __launch_bounds__(256) void scan1(const int* __restrict__ in, int* __restrict__ out,
                                             int* __restrict__ blksum, int n) {
    __shared__ int sh[256];
    int base = blockIdx.x * SCAN_ELEMS + threadIdx.x * SCAN_VPT;
    int v[SCAN_VPT];
    int sum = 0;
    #pragma unroll
    for (int j = 0; j < SCAN_VPT; ++j) {
        v[j] = (base + j < n) ? in[base + j] : 0;
        sum += v[j];
    }
    sh[threadIdx.x] = sum;
    __syncthreads();
    for (int off = 1; off < 256; off <<= 1) {
        int t = (threadIdx.x >= off) ? sh[threadIdx.x - off] : 0;
        __syncthreads();
        sh[threadIdx.x] += t;
        __syncthreads();
    }
    if (threadIdx.x == 255) blksum[blockIdx.x] = sh[255];
    int run = sh[threadIdx.x] - sum;
    #pragma unroll
    for (int j = 0; j < SCAN_VPT; ++j) {
        if (base + j < n) out[base + j] = run;
        run += v[j];
    }
}

__global__ __launch_bounds__(256) void scan2(int* __restrict__ blksum, int nb) {
    __shared__ int sh[256];
    int t = threadIdx.x;
    int v = (t < nb) ? blksum[t] : 0;
    sh[t] = v;
    __syncthreads();
    for (int off = 1; off < 256; off <<= 1) {
        int u = (t >= off) ? sh[t - off] : 0;
        __syncthreads();
        sh[t] += u;
        __syncthreads();
    }
    if (t < nb) blksum[t] = sh[t] - v;
}

// ==================== W1 -> bf16 transposed [32][512] (once) ====================
__global__ __launch_bounds__(256) void wconv(const float* __restrict__ W, unsigned short* __restrict__ W1T) {
    int gidx = blockIdx.x * 256 + threadIdx.x;  // 0..16383
    if (gidx < 32 * 512) {
        int c = gidx >> 9, k = gidx & 511;
        W1T[gidx] = f2bf(W[(size_t)k * 32 + c]);
    }
}

// ==================== within-bucket counting sort -> dst-sorted CSR + degree/dis ====================
#define SORT_CAP 8192

__global__ __launch_bounds__(512) void sort_bucket(const int* __restrict__ pairs,
        const int* __restrict__ scanG, const int* __restrict__ blksum, int B, int NB,
        int* __restrict__ csr_src, int* __restrict__ node_start,
        int* __restrict__ cnt, float* __restrict__ dis, int n, int E) {
    __shared__ int keys[SORT_CAP];
    __shared__ int lcnt[BKT_NODES];
    __shared__ int lscan[BKT_NODES];
    __shared__ int lfill[BKT_NODES];
    int bkt = blockIdx.x, tid = threadIdx.x;
    size_t idx0 = (size_t)bkt * B;
    int e0 = scanG[idx0] + blksum[idx0 >> 11];
    int e1 = E;
    if (bkt + 1 < NB) {
        size_t idx1 = (size_t)(bkt + 1) * B;
        e1 = scanG[idx1] + blksum[idx1 >> 11];
    }
    int m = e1 - e0;
    if (tid < BKT_NODES) { lcnt[tid] = 0; lfill[tid] = 0; }
    __syncthreads();
    for (int i = tid; i < m; i += 512) {
        int k = pairs[e0 + i];
        if (i < SORT_CAP) keys[i] = k;
        atomicAdd(&lcnt[k & (BKT_NODES - 1)], 1);
    }
    __syncthreads();
    if (tid == 0) {
        int run = 0;
        for (int i = 0; i < BKT_NODES; ++i) { lscan[i] = run; run += lcnt[i]; }
    }
    __syncthreads();
    int nb0 = bkt << BKT_SHIFT;
    if (tid < BKT_NODES && nb0 + tid < n) {
        int deg = lcnt[tid];
        node_start[nb0 + tid] = e0 + lscan[tid];
        cnt[nb0 + tid] = deg;
        dis[nb0 + tid] = rsqrtf((float)deg + 1.0f);
    }
    for (int i = tid; i < m; i += 512) {
        int k = (i < SORT_CAP) ? keys[i] : pairs[e0 + i];
        int d = k & (BKT_NODES - 1);
        int pos = lscan[d] + atomicAdd(&lfill[d], 1);
        csr_src[e0 + pos] = k >> BKT_SHIFT;
    }
}

// ==================== gemm1 (MFMA): 512->32 bf16, 64 nodes/block, 4 waves ====================
// W1T (bf16, [32][512]) preconverted; per-block LDS copy is pure ushort8 moves.

__global__ __launch_bounds__(256) void gemm1_mfma(const float* __restrict__ x, const unsigned short* __restrict__ W1T,
                                                  const float* __restrict__ dis, unsigned short* __restrict__ g, int n) {
    __shared__ __attribute__((aligned(16))) unsigned short wT[32][520];  // [col][k], +8 pad
    __shared__ __attribute__((aligned(16))) unsigned short xb[64][72];   // [nodeLocal][k-chunk 64], +8 pad
    int tid = threadIdx.x;
    int node0 = blockIdx.x * 64;

    // one-time: copy W1T bf16 into LDS (2048 ushort8 loads)
    #pragma unroll
    for (int r = 0; r < 8; ++r) {
        int u8 = tid + r * 256;            // ushort8 index 0..2047
        int c = u8 >> 6, kq = (u8 & 63) * 8;
        *(u16x8*)(&wT[c][kq]) = *(const u16x8*)(W1T + (size_t)c * 512 + kq);
    }

    int wv_ = tid >> 6;       // wave 0..3 -> node sub-tile
    int lane = tid & 63;
    int mrow = lane & 15;     // A row / B col / D col
    int kg = lane >> 4;       // k-group 0..3 (8 k each)
    f32x4 acc0 = {0.f, 0.f, 0.f, 0.f};
    f32x4 acc1 = {0.f, 0.f, 0.f, 0.f};

    for (int k0 = 0; k0 < 512; k0 += 64) {
        __syncthreads();  // xb reuse + (iter 0) W staging done
        // stage x chunk: 64 nodes x 64 k, f32 -> bf16
        #pragma unroll
        for (int r = 0; r < 4; ++r) {
            int fi = tid + r * 256;       // float4 index 0..1023
            int nd = fi >> 4, kq = (fi & 15) * 4;
            int gn = min(node0 + nd, n - 1);
            float4 xv = *(const float4*)(x + (size_t)gn * 512 + k0 + kq);
            ushort4 p;
            p.x = f2bf(xv.x); p.y = f2bf(xv.y); p.z = f2bf(xv.z); p.w = f2bf(xv.w);
            *(ushort4*)(&xb[nd][kq]) = p;
        }
        __syncthreads();
        #pragma unroll
        for (int ks = 0; ks < 2; ++ks) {
            bf16x8 a  = *(const bf16x8*)(&xb[wv_ * 16 + mrow][ks * 32 + kg * 8]);
            bf16x8 b0 = *(const bf16x8*)(&wT[mrow][k0 + ks * 32 + kg * 8]);
            bf16x8 b1 = *(const bf16x8*)(&wT[16 + mrow][k0 + ks * 32 + kg * 8]);
            acc0 = __builtin_amdgcn_mfma_f32_16x16x32_bf16(a, b0, acc0, 0, 0, 0);
            acc1 = __builtin_amdgcn_mfma_f32_16x16x32_bf16(a, b1, acc1, 0, 0, 0);
        }
    }
    // D: col = lane&15, row = (lane>>4)*4 + j
    #pragma unroll
    for (int j = 0; j < 4; ++j) {
        int node = node0 + wv_ * 16 + kg * 4 + j;
        if (node < n) {
            float dv = dis[node];
            g[(size_t)node * 32 + mrow]      = f2bf(acc0[j] * dv);
            g[(size_t)node * 32 + 16 + mrow] = f2bf(acc1[j] * dv);
        }
    }
}

// ==================== gather1: paired-bf16 CSR gather F=32 + fused (relu -> @W2 -> *dis) ====================
// lane = (fpair 0..15, j 0..3): 4 edges in flight per load instruction.

__global__ __launch_bounds__(256) void gather1(const int* __restrict__ csr_src,
        const int* __restrict__ start, const int* __restrict__ cnt,
        const unsigned short* __restrict__ g1, const float* __restrict__ dis,
        const float* __restrict__ b1, const float* __restrict__ W2,
        unsigned short* __restrict__ g2, int n) {
    __shared__ float w2s[32 * 16];
    for (int i = threadIdx.x; i < 512; i += 256) w2s[i] = W2[i];
    __syncthreads();
    int node = blockIdx.x * 4 + (threadIdx.x >> 6);
    if (node >= n) return;
    int lane = threadIdx.x & 63;
    int fpair = lane & 15;       // features 2*fpair, 2*fpair+1
    int j = lane >> 4;           // 0..3
    int i0 = start[node], i1 = i0 + cnt[node];
    float alo = 0.f, ahi = 0.f;
    int i = i0 + j;
    for (; i + 12 < i1; i += 16) {
        int s1 = csr_src[i];
        int s2 = csr_src[i + 4];
        int s3 = csr_src[i + 8];
        int s4 = csr_src[i + 12];
        unsigned v1 = *(const unsigned*)(g1 + (size_t)s1 * 32 + fpair * 2);
        unsigned v2 = *(const unsigned*)(g1 + (size_t)s2 * 32 + fpair * 2);
        unsigned v3 = *(const unsigned*)(g1 + (size_t)s3 * 32 + fpair * 2);
        unsigned v4 = *(const unsigned*)(g1 + (size_t)s4 * 32 + fpair * 2);
        alo += bflo(v1) + bflo(v2) + bflo(v3) + bflo(v4);
        ahi += bfhi(v1) + bfhi(v2) + bfhi(v3) + bfhi(v4);
    }
    for (; i < i1; i += 4) {
        unsigned v = *(const unsigned*)(g1 + (size_t)csr_src[i] * 32 + fpair * 2);
        alo += bflo(v); ahi += bfhi(v);
    }
    alo += __shfl_xor(alo, 16); alo += __shfl_xor(alo, 32);
    ahi += __shfl_xor(ahi, 16); ahi += __shfl_xor(ahi, 32);
    float dv = dis[node];
    unsigned sv = *(const unsigned*)(g1 + (size_t)node * 32 + fpair * 2);
    float vlo = fmaxf((alo + bflo(sv)) * dv + b1[2 * fpair], 0.f);
    float vhi = fmaxf((ahi + bfhi(sv)) * dv + b1[2 * fpair + 1], 0.f);
    // fused 32->16 projection: col c = lane&15, j handles q = 4j..4j+3
    int c = fpair;
    float p = 0.f;
    #pragma unroll
    for (int qq = 0; qq < 4; ++qq) {
        int q = j * 4 + qq;
        float xlo = __shfl(vlo, q);
        float xhi = __shfl(vhi, q);
        p = fmaf(xlo, w2s[(2 * q) * 16 + c], p);
        p = fmaf(xhi, w2s[(2 * q + 1) * 16 + c], p);
    }
    p += __shfl_xor(p, 16);
    p += __shfl_xor(p, 32);
    if (lane < 16) g2[(size_t)node * 16 + c] = f2bf(p * dv);
}

// ==================== gather2: paired-bf16 CSR gather F=16 + fused (relu -> @W3 -> *dis) ====================
// lane = (fpair 0..7, j 0..7): 8 edges in flight per load instruction.

__global__ __launch_bounds__(256) void gather2(const int* __restrict__ csr_src,
        const int* __restrict__ start, const int* __restrict__ cnt,
        const unsigned short* __restrict__ g2, const float* __restrict__ dis,
        const float* __restrict__ b2, const float* __restrict__ W3,
        unsigned short* __restrict__ g3, int n) {
    __shared__ float w3s[16 * 16];
    if (threadIdx.x < 256) {
        int k = threadIdx.x >> 4, c = threadIdx.x & 15;
        w3s[threadIdx.x] = (c < 11) ? W3[(size_t)k * 11 + c] : 0.f;
    }
    __syncthreads();
    int node = blockIdx.x * 4 + (threadIdx.x >> 6);
    if (node >= n) return;
    int lane = threadIdx.x & 63;
    int fpair = lane & 7;        // features 2*fpair, 2*fpair+1
    int j = lane >> 3;           // 0..7
    int i0 = start[node], i1 = i0 + cnt[node];
    float alo = 0.f, ahi = 0.f;
    int i = i0 + j;
    for (; i + 24 < i1; i += 32) {
        int s1 = csr_src[i];
        int s2 = csr_src[i + 8];
        int s3 = csr_src[i + 16];
        int s4 = csr_src[i + 24];
        unsigned v1 = *(const unsigned*)(g2 + (size_t)s1 * 16 + fpair * 2);
        unsigned v2 = *(const unsigned*)(g2 + (size_t)s2 * 16 + fpair * 2);
        unsigned v3 = *(const unsigned*)(g2 + (size_t)s3 * 16 + fpair * 2);
        unsigned v4 = *(const unsigned*)(g2 + (size_t)s4 * 16 + fpair * 2);
        alo += bflo(v1) + bflo(v2) + bflo(v3) + bflo(v4);
        ahi += bfhi(v1) + bfhi(v2) + bfhi(v3) + bfhi(v4);
    }
    for (; i < i1; i += 8) {
        unsigned v = *(const unsigned*)(g2 + (size_t)csr_src[i] * 16 + fpair * 2);
        alo += bflo(v); ahi += bfhi(v);
    }
    alo += __shfl_xor(alo, 8); alo += __shfl_xor(alo, 16); alo += __shfl_xor(alo, 32);
    ahi += __shfl_xor(ahi, 8); ahi += __shfl_xor(ahi, 16); ahi += __shfl_xor(ahi, 32);
    float dv = dis[node];
    unsigned sv = *(const unsigned*)(g2 + (size_t)node * 16 + fpair * 2);
    float vlo = fmaxf((alo + bflo(sv)) * dv + b2[2 * fpair], 0.f);
    float vhi = fmaxf((ahi + bfhi(sv)) * dv + b2[2 * fpair + 1], 0.f);
    // fused 16->16(11 padded) projection: col c = lane&15, j2 = lane>>4 handles k = 4*j2..4*j2+3
    int c = lane & 15;
    int j2 = lane >> 4;
    float p = 0.f;
    #pragma unroll
    for (int kk = 0; kk < 4; ++kk) {
        int k = j2 * 4 + kk;  // k parity == kk parity (wave-uniform)
        float xk = (kk & 1) ? __shfl(vhi, k >> 1) : __shfl(vlo, k >> 1);
        p = fmaf(xk, w3s[k * 16 + c], p);
    }
    p += __shfl_xor(p, 16);
    p += __shfl_xor(p, 32);
    if (lane < 16) g3[(size_t)node * 16 + c] = f2bf(p * dv);
}

// ==================== gather3: paired-bf16 F=16 gather + self + bias + log_softmax ====================

__global__ __launch_bounds__(256) void gather3(const int* __restrict__ csr_src,
        const int* __restrict__ start, const int* __restrict__ cnt,
        const unsigned short* __restrict__ g, const float* __restrict__ dis,
        const float* __restrict__ bias, float* __restrict__ out, int n) {
    int node = blockIdx.x * 4 + (threadIdx.x >> 6);
    if (node >= n) return;
    int lane = threadIdx.x & 63;
    int fpair = lane & 7;
    int j = lane >> 3;
    int i0 = start[node], i1 = i0 + cnt[node];
    float alo = 0.f, ahi = 0.f;
    int i = i0 + j;
    for (; i + 24 < i1; i += 32) {
        int s1 = csr_src[i];
        int s2 = csr_src[i + 8];
        int s3 = csr_src[i + 16];
        int s4 = csr_src[i + 24];
        unsigned v1 = *(const unsigned*)(g + (size_t)s1 * 16 + fpair * 2);
        unsigned v2 = *(const unsigned*)(g + (size_t)s2 * 16 + fpair * 2);
        unsigned v3 = *(const unsigned*)(g + (size_t)s3 * 16 + fpair * 2);
        unsigned v4 = *(const unsigned*)(g + (size_t)s4 * 16 + fpair * 2);
        alo += bflo(v1) + bflo(v2) + bflo(v3) + bflo(v4);
        ahi += bfhi(v1) + bfhi(v2) + bfhi(v3) + bfhi(v4);
    }
    for (; i < i1; i += 8) {
        unsigned v = *(const unsigned*)(g + (size_t)csr_src[i] * 16 + fpair * 2);
        alo += bflo(v); ahi += bfhi(v);
    }
    alo += __shfl_xor(alo, 8); alo += __shfl_xor(alo, 16); alo += __shfl_xor(alo, 32);
    ahi += __shfl_xor(ahi, 8); ahi += __shfl_xor(ahi, 16); ahi += __shfl_xor(ahi, 32);
    unsigned sv = *(const unsigned*)(g + (size_t)node * 16 + fpair * 2);
    float dvn = dis[node];
    int flo = 2 * fpair, fhi = 2 * fpair + 1;
    bool oklo = flo < 11, okhi = fhi < 11;
    float vlo = (alo + bflo(sv)) * dvn + (oklo ? bias[flo] : 0.f);
    float vhi = (ahi + bfhi(sv)) * dvn + (okhi ? bias[fhi] : 0.f);
    float m = fmaxf(oklo ? vlo : -3.0e38f, okhi ? vhi : -3.0e38f);
    m = fmaxf(m, __shfl_xor(m, 1));
    m = fmaxf(m, __shfl_xor(m, 2));
    m = fmaxf(m, __shfl_xor(m, 4));
    float s = (oklo ? __expf(vlo - m) : 0.f) + (okhi ? __expf(vhi - m) : 0.f);
    s += __shfl_xor(s, 1); s += __shfl_xor(s, 2); s += __shfl_xor(s, 4);
    float ls = __logf(s) + m;
    if (lane < 8) {
        if (oklo) out[(size_t)node * 11 + flo] = vlo - ls;
        if (okhi) out[(size_t)node * 11 + fhi] = vhi - ls;
    }
}

// ==================== launch ====================

extern "C" void kernel_launch(void* const* d_in, const int* in_sizes, int n_in,
                              void* d_out, int out_size, void* d_ws, size_t ws_size,
                              hipStream_t stream) {
    const float* x  = (const float*)d_in[0];
    const int*   ei = (const int*)d_in[1];
    const float* W1 = (const float*)d_in[2];
    const float* b1 = (const float*)d_in[3];
    const float* W2 = (const float*)d_in[4];
    const float* b2 = (const float*)d_in[5];
    const float* W3 = (const float*)d_in[6];
    const float* b3 = (const float*)d_in[7];
    float* out = (float*)d_out;

    const int n = in_sizes[0] / 512;
    const int E = in_sizes[1] / 2;
    const int* src = ei;
    const int* dst = ei + E;

    const int NB = (n + BKT_NODES - 1) >> BKT_SHIFT;      // 782
    const int B  = (E + CHUNK - 1) / CHUNK;               // 98
    const int NBB = NB * B;
    const int nb_scan = (NBB + SCAN_ELEMS - 1) / SCAN_ELEMS;

    // workspace layout (4B elements)
    int* ws0 = (int*)d_ws;
    size_t off = 0;
    int*   cnt     = ws0 + off; off += (size_t)n;
    float* dis     = (float*)(ws0 + off); off += (size_t)n;
    int*   nstart  = ws0 + off; off += (size_t)n;
    int*   scanG   = ws0 + off; off += (size_t)NBB;
    int*   blksum  = ws0 + off; off += 256;
    int*   pairs   = ws0 + off; off += (size_t)E;
    int*   csr_src = ws0 + off; off += (size_t)E;
    unsigned short* g1 = (unsigned short*)(ws0 + off); off += (size_t)n * 16;  // n*32 bf16
    unsigned short* g2 = (unsigned short*)(ws0 + off); off += (size_t)n * 8;   // n*16 bf16
    unsigned short* g3 = (unsigned short*)(ws0 + off); off += (size_t)n * 8;   // n*16 bf16
    unsigned short* W1T = (unsigned short*)(ws0 + off); off += 8192;           // 32x512 bf16
    int*   histG   = (int*)g1;  // alias: histG dead before gemm1 writes g1

    // ---- bucket binning + within-bucket counting sort -> dst-sorted CSR + deg/dis ----
    hist_k<<<B, 512, 0, stream>>>(dst, histG, B, NB, E);
    scan1<<<nb_scan, 256, 0, stream>>>(histG, scanG, blksum, NBB);
    scan2<<<1, 256, 0, stream>>>(blksum, nb_scan);
    wconv<<<64, 256, 0, stream>>>(W1, W1T);
    scatter_k<<<B, 512, 0, stream>>>(src, dst, scanG, blksum, pairs, B, NB, E);
    sort_bucket<<<NB, 512, 0, stream>>>(pairs, scanG, blksum, B, NB, csr_src, nstart, cnt, dis, n, E);

    // ---- layer 1 GEMM (MFMA), then fused gather chains ----
    gemm1_mfma<<<(n + 63) / 64, 256, 0, stream>>>(x, W1T, dis, g1, n);
    gather1<<<(n + 3) / 4, 256, 0, stream>>>(csr_src, nstart, cnt, g1, dis, b1, W2, g2, n);
    gather2<<<(n + 3) / 4, 256, 0, stream>>>(csr_src, nstart, cnt, g2, dis, b2, W3, g3, n);
    gather3<<<(n + 3) / 4, 256, 0, stream>>>(csr_src, nstart, cnt, g3, dis, b3, out, n);
}

// Round 14
// 290.954 us; speedup vs baseline: 1.3448x; 1.0958x over previous
//
#include <hip/hip_runtime.h>
#include <hip/hip_bf16.h>

// ---- bf16 helpers (manual, finite-value RNE) ----
static __device__ __forceinline__ unsigned short f2bf(float f) {
    unsigned u = __float_as_uint(f);
    unsigned r = (u + 0x7FFF + ((u >> 16) & 1)) >> 16;
    return (unsigned short)r;
}
static __device__ __forceinline__ float bf2f(unsigned short h) {
    return __uint_as_float(((unsigned)h) << 16);
}
static __device__ __forceinline__ float bflo(unsigned v) { return __uint_as_float(v << 16); }
static __device__ __forceinline__ float bfhi(unsigned v) { return __uint_as_float(v & 0xFFFF0000u); }
// packed 2xf32 -> 2xbf16 (RNE) via v_cvt_pk_bf16_f32; memory order: a low, b high
static __device__ __forceinline__ unsigned pack2bf(float a, float b) {
    __hip_bfloat162 h2 = __float22bfloat162_rn(float2{a, b});
    union { __hip_bfloat162 h; unsigned u; } cv;
    cv.h = h2;
    return cv.u;
}

typedef __attribute__((ext_vector_type(8))) short bf16x8;
typedef __attribute__((ext_vector_type(8))) unsigned short u16x8;
typedef __attribute__((ext_vector_type(4))) float f32x4;

// ==================== bucket binning ====================
#define BKT_SHIFT 7
#define BKT_NODES 128
#define CHUNK 16384  // edges per hist/scatter block (512 thr x 32) -> B=196 blocks

__global__ __launch_bounds__(512) void hist_k(const int* __restrict__ dst, int* __restrict__ histG,
                                              int B, int NB, int E) {
    __shared__ int hist[1024];
    int tid = threadIdx.x;
    for (int i = tid; i < NB; i += 512) hist[i] = 0;
    __syncthreads();
    int base = blockIdx.x * CHUNK;
    for (int i = tid; i < CHUNK; i += 512) {
        int e = base + i;
        if (e >= E) break;
        atomicAdd(&hist[dst[e] >> BKT_SHIFT], 1);
    }
    __syncthreads();
    for (int i = tid; i < NB; i += 512) histG[(size_t)i * B + blockIdx.x] = hist[i];
}

// scatter with scan3 folded in (adds blksum[idx>>11] on the fly)
__global__ __launch_bounds__(512) void scatter_k(const int* __restrict__ src, const int* __restrict__ dst,
                                                 const int* __restrict__ scanG, const int* __restrict__ blksum,
                                                 int* __restrict__ pairs, int B, int NB, int E) {
    __shared__ int sbase[1024];
    __shared__ int scnt[1024];
    int tid = threadIdx.x;
    for (int i = tid; i < NB; i += 512) {
        size_t idx = (size_t)i * B + blockIdx.x;
        sbase[i] = scanG[idx] + blksum[idx >> 11];
        scnt[i] = 0;
    }
    __syncthreads();
    int base = blockIdx.x * CHUNK;
    for (int i = tid; i < CHUNK; i += 512) {
        int e = base + i;
        if (e >= E) break;
        int d = dst[e], s = src[e];
        int b = d >> BKT_SHIFT;
        int r = atomicAdd(&scnt[b], 1);
        pairs[sbase[b] + r] = (s << BKT_SHIFT) | (d & (BKT_NODES - 1));
    }
}

// ==================== scan (exclusive), 256 thr x 8 = 2048 elems/block ====================
#define SCAN_VPT 8
#define SCAN_ELEMS 2048

__global__ __launch_bounds__(256) void scan1(const int* __restrict__ in, int* __restrict__ out,
                                             int* __restrict__ blksum, int n) {
    __shared__ int sh[256];
    int base = blockIdx.x * SCAN_ELEMS + threadIdx.x * SCAN_VPT;
    int v[SCAN_VPT];
    int sum = 0;
    #pragma unroll
    for (int j = 0; j < SCAN_VPT; ++j) {
        v[j] = (base + j < n) ? in[base + j] : 0;
        sum += v[j];
    }
    sh[threadIdx.x] = sum;
    __syncthreads();
    for (int off = 1; off < 256; off <<= 1) {
        int t = (threadIdx.x >= off) ? sh[threadIdx.x - off] : 0;
        __syncthreads();
        sh[threadIdx.x] += t;
        __syncthreads();
    }
    if (threadIdx.x == 255) blksum[blockIdx.x] = sh[255];
    int run = sh[threadIdx.x] - sum;
    #pragma unroll
    for (int j = 0; j < SCAN_VPT; ++j) {
        if (base + j < n) out[base + j] = run;
        run += v[j];
    }
}

__global__ __launch_bounds__(256) void scan2(int* __restrict__ blksum, int nb) {
    __shared__ int sh[256];
    int t = threadIdx.x;
    int v = (t < nb) ? blksum[t] : 0;
    sh[t] = v;
    __syncthreads();
    for (int off = 1; off < 256; off <<= 1) {
        int u = (t >= off) ? sh[t - off] : 0;
        __syncthreads();
        sh[t] += u;
        __syncthreads();
    }
    if (t < nb) blksum[t] = sh[t] - v;
}

// ==================== W1 -> bf16 transposed [32][512] (once) ====================
__global__ __launch_bounds__(256) void wconv(const float* __restrict__ W, unsigned short* __restrict__ W1T) {
    int gidx = blockIdx.x * 256 + threadIdx.x;  // 0..16383
    if (gidx < 32 * 512) {
        int c = gidx >> 9, k = gidx & 511;
        W1T[gidx] = f2bf(W[(size_t)k * 32 + c]);
    }
}

// ==================== within-bucket counting sort -> dst-sorted CSR + degree/dis ====================
#define SORT_CAP 8192

__global__ __launch_bounds__(512) void sort_bucket(const int* __restrict__ pairs,
        const int* __restrict__ scanG, const int* __restrict__ blksum, int B, int NB,
        int* __restrict__ csr_src, int* __restrict__ node_start,
        int* __restrict__ cnt, float* __restrict__ dis, int n, int E) {
    __shared__ int keys[SORT_CAP];
    __shared__ int lcnt[BKT_NODES];
    __shared__ int lscan[BKT_NODES];
    __shared__ int lfill[BKT_NODES];
    int bkt = blockIdx.x, tid = threadIdx.x;
    size_t idx0 = (size_t)bkt * B;
    int e0 = scanG[idx0] + blksum[idx0 >> 11];
    int e1 = E;
    if (bkt + 1 < NB) {
        size_t idx1 = (size_t)(bkt + 1) * B;
        e1 = scanG[idx1] + blksum[idx1 >> 11];
    }
    int m = e1 - e0;
    if (tid < BKT_NODES) { lcnt[tid] = 0; lfill[tid] = 0; }
    __syncthreads();
    for (int i = tid; i < m; i += 512) {
        int k = pairs[e0 + i];
        if (i < SORT_CAP) keys[i] = k;
        atomicAdd(&lcnt[k & (BKT_NODES - 1)], 1);
    }
    __syncthreads();
    // wave-0 parallel exclusive scan of lcnt[128] (2 elems/lane)
    if (tid < 64) {
        int c0 = lcnt[2 * tid], c1 = lcnt[2 * tid + 1];
        int s = c0 + c1;
        #pragma unroll
        for (int off = 1; off < 64; off <<= 1) {
            int t = __shfl_up(s, off);
            if (tid >= off) s += t;
        }
        lscan[2 * tid]     = s - c1 - c0;
        lscan[2 * tid + 1] = s - c1;
    }
    __syncthreads();
    int nb0 = bkt << BKT_SHIFT;
    if (tid < BKT_NODES && nb0 + tid < n) {
        int deg = lcnt[tid];
        node_start[nb0 + tid] = e0 + lscan[tid];
        cnt[nb0 + tid] = deg;
        dis[nb0 + tid] = rsqrtf((float)deg + 1.0f);
    }
    for (int i = tid; i < m; i += 512) {
        int k = (i < SORT_CAP) ? keys[i] : pairs[e0 + i];
        int d = k & (BKT_NODES - 1);
        int pos = lscan[d] + atomicAdd(&lfill[d], 1);
        csr_src[e0 + pos] = k >> BKT_SHIFT;
    }
}

// ==================== gemm1 (MFMA): 512->32 bf16, 64 nodes/block, 4 waves ====================
// W1T (bf16, [32][512]) preconverted; x staging uses packed v_cvt_pk_bf16_f32.

__global__ __launch_bounds__(256) void gemm1_mfma(const float* __restrict__ x, const unsigned short* __restrict__ W1T,
                                                  const float* __restrict__ dis, unsigned short* __restrict__ g, int n) {
    __shared__ __attribute__((aligned(16))) unsigned short wT[32][520];  // [col][k], +8 pad
    __shared__ __attribute__((aligned(16))) unsigned short xb[64][72];   // [nodeLocal][k-chunk 64], +8 pad
    int tid = threadIdx.x;
    int node0 = blockIdx.x * 64;

    // one-time: copy W1T bf16 into LDS (2048 ushort8 loads)
    #pragma unroll
    for (int r = 0; r < 8; ++r) {
        int u8 = tid + r * 256;            // ushort8 index 0..2047
        int c = u8 >> 6, kq = (u8 & 63) * 8;
        *(u16x8*)(&wT[c][kq]) = *(const u16x8*)(W1T + (size_t)c * 512 + kq);
    }

    int wv_ = tid >> 6;       // wave 0..3 -> node sub-tile
    int lane = tid & 63;
    int mrow = lane & 15;     // A row / B col / D col
    int kg = lane >> 4;       // k-group 0..3 (8 k each)
    f32x4 acc0 = {0.f, 0.f, 0.f, 0.f};
    f32x4 acc1 = {0.f, 0.f, 0.f, 0.f};

    for (int k0 = 0; k0 < 512; k0 += 64) {
        __syncthreads();  // xb reuse + (iter 0) W staging done
        // stage x chunk: 64 nodes x 64 k, f32 -> bf16 (packed cvt)
        #pragma unroll
        for (int r = 0; r < 4; ++r) {
            int fi = tid + r * 256;       // float4 index 0..1023
            int nd = fi >> 4, kq = (fi & 15) * 4;
            int gn = min(node0 + nd, n - 1);
            float4 xv = *(const float4*)(x + (size_t)gn * 512 + k0 + kq);
            uint2 pw;
            pw.x = pack2bf(xv.x, xv.y);
            pw.y = pack2bf(xv.z, xv.w);
            *(uint2*)(&xb[nd][kq]) = pw;
        }
        __syncthreads();
        #pragma unroll
        for (int ks = 0; ks < 2; ++ks) {
            bf16x8 a  = *(const bf16x8*)(&xb[wv_ * 16 + mrow][ks * 32 + kg * 8]);
            bf16x8 b0 = *(const bf16x8*)(&wT[mrow][k0 + ks * 32 + kg * 8]);
            bf16x8 b1 = *(const bf16x8*)(&wT[16 + mrow][k0 + ks * 32 + kg * 8]);
            acc0 = __builtin_amdgcn_mfma_f32_16x16x32_bf16(a, b0, acc0, 0, 0, 0);
            acc1 = __builtin_amdgcn_mfma_f32_16x16x32_bf16(a, b1, acc1, 0, 0, 0);
        }
    }
    // D: col = lane&15, row = (lane>>4)*4 + j
    #pragma unroll
    for (int j = 0; j < 4; ++j) {
        int node = node0 + wv_ * 16 + kg * 4 + j;
        if (node < n) {
            float dv = dis[node];
            g[(size_t)node * 32 + mrow]      = f2bf(acc0[j] * dv);
            g[(size_t)node * 32 + 16 + mrow] = f2bf(acc1[j] * dv);
        }
    }
}

// ==================== gather1: paired-bf16 CSR gather F=32 + fused (relu -> @W2 -> *dis) ====================
// lane = (fpair 0..15, j 0..3): 4 edges in flight per load instruction.

__global__ __launch_bounds__(256) void gather1(const int* __restrict__ csr_src,
        const int* __restrict__ start, const int* __restrict__ cnt,
        const unsigned short* __restrict__ g1, const float* __restrict__ dis,
        const float* __restrict__ b1, const float* __restrict__ W2,
        unsigned short* __restrict__ g2, int n) {
    __shared__ float w2s[32 * 16];
    for (int i = threadIdx.x; i < 512; i += 256) w2s[i] = W2[i];
    __syncthreads();
    int node = blockIdx.x * 4 + (threadIdx.x >> 6);
    if (node >= n) return;
    int lane = threadIdx.x & 63;
    int fpair = lane & 15;       // features 2*fpair, 2*fpair+1
    int j = lane >> 4;           // 0..3
    int i0 = start[node], i1 = i0 + cnt[node];
    float alo = 0.f, ahi = 0.f;
    int i = i0 + j;
    for (; i + 12 < i1; i += 16) {
        int s1 = csr_src[i];
        int s2 = csr_src[i + 4];
        int s3 = csr_src[i + 8];
        int s4 = csr_src[i + 12];
        unsigned v1 = *(const unsigned*)(g1 + (size_t)s1 * 32 + fpair * 2);
        unsigned v2 = *(const unsigned*)(g1 + (size_t)s2 * 32 + fpair * 2);
        unsigned v3 = *(const unsigned*)(g1 + (size_t)s3 * 32 + fpair * 2);
        unsigned v4 = *(const unsigned*)(g1 + (size_t)s4 * 32 + fpair * 2);
        alo += bflo(v1) + bflo(v2) + bflo(v3) + bflo(v4);
        ahi += bfhi(v1) + bfhi(v2) + bfhi(v3) + bfhi(v4);
    }
    for (; i < i1; i += 4) {
        unsigned v = *(const unsigned*)(g1 + (size_t)csr_src[i] * 32 + fpair * 2);
        alo += bflo(v); ahi += bfhi(v);
    }
    alo += __shfl_xor(alo, 16); alo += __shfl_xor(alo, 32);
    ahi += __shfl_xor(ahi, 16); ahi += __shfl_xor(ahi, 32);
    float dv = dis[node];
    unsigned sv = *(const unsigned*)(g1 + (size_t)node * 32 + fpair * 2);
    float vlo = fmaxf((alo + bflo(sv)) * dv + b1[2 * fpair], 0.f);
    float vhi = fmaxf((ahi + bfhi(sv)) * dv + b1[2 * fpair + 1], 0.f);
    // fused 32->16 projection: col c = lane&15, j handles q = 4j..4j+3
    int c = fpair;
    float p = 0.f;
    #pragma unroll
    for (int qq = 0; qq < 4; ++qq) {
        int q = j * 4 + qq;
        float xlo = __shfl(vlo, q);
        float xhi = __shfl(vhi, q);
        p = fmaf(xlo, w2s[(2 * q) * 16 + c], p);
        p = fmaf(xhi, w2s[(2 * q + 1) * 16 + c], p);
    }
    p += __shfl_xor(p, 16);
    p += __shfl_xor(p, 32);
    if (lane < 16) g2[(size_t)node * 16 + c] = f2bf(p * dv);
}

// ==================== gather2: paired-bf16 CSR gather F=16 + fused (relu -> @W3 -> *dis) ====================
// lane = (fpair 0..7, j 0..7): 8 edges in flight per load instruction.

__global__ __launch_bounds__(256) void gather2(const int* __restrict__ csr_src,
        const int* __restrict__ start, const int* __restrict__ cnt,
        const unsigned short* __restrict__ g2, const float* __restrict__ dis,
        const float* __restrict__ b2, const float* __restrict__ W3,
        unsigned short* __restrict__ g3, int n) {
    __shared__ float w3s[16 * 16];
    if (threadIdx.x < 256) {
        int k = threadIdx.x >> 4, c = threadIdx.x & 15;
        w3s[threadIdx.x] = (c < 11) ? W3[(size_t)k * 11 + c] : 0.f;
    }
    __syncthreads();
    int node = blockIdx.x * 4 + (threadIdx.x >> 6);
    if (node >= n) return;
    int lane = threadIdx.x & 63;
    int fpair = lane & 7;        // features 2*fpair, 2*fpair+1
    int j = lane >> 3;           // 0..7
    int i0 = start[node], i1 = i0 + cnt[node];
    float alo = 0.f, ahi = 0.f;
    int i = i0 + j;
    for (; i + 24 < i1; i += 32) {
        int s1 = csr_src[i];
        int s2 = csr_src[i + 8];
        int s3 = csr_src[i + 16];
        int s4 = csr_src[i + 24];
        unsigned v1 = *(const unsigned*)(g2 + (size_t)s1 * 16 + fpair * 2);
        unsigned v2 = *(const unsigned*)(g2 + (size_t)s2 * 16 + fpair * 2);
        unsigned v3 = *(const unsigned*)(g2 + (size_t)s3 * 16 + fpair * 2);
        unsigned v4 = *(const unsigned*)(g2 + (size_t)s4 * 16 + fpair * 2);
        alo += bflo(v1) + bflo(v2) + bflo(v3) + bflo(v4);
        ahi += bfhi(v1) + bfhi(v2) + bfhi(v3) + bfhi(v4);
    }
    for (; i < i1; i += 8) {
        unsigned v = *(const unsigned*)(g2 + (size_t)csr_src[i] * 16 + fpair * 2);
        alo += bflo(v); ahi += bfhi(v);
    }
    alo += __shfl_xor(alo, 8); alo += __shfl_xor(alo, 16); alo += __shfl_xor(alo, 32);
    ahi += __shfl_xor(ahi, 8); ahi += __shfl_xor(ahi, 16); ahi += __shfl_xor(ahi, 32);
    float dv = dis[node];
    unsigned sv = *(const unsigned*)(g2 + (size_t)node * 16 + fpair * 2);
    float vlo = fmaxf((alo + bflo(sv)) * dv + b2[2 * fpair], 0.f);
    float vhi = fmaxf((ahi + bfhi(sv)) * dv + b2[2 * fpair + 1], 0.f);
    // fused 16->16(11 padded) projection: col c = lane&15, j2 = lane>>4 handles k = 4*j2..4*j2+3
    int c = lane & 15;
    int j2 = lane >> 4;
    float p = 0.f;
    #pragma unroll
    for (int kk = 0; kk < 4; ++kk) {
        int k = j2 * 4 + kk;  // k parity == kk parity (wave-uniform)
        float xk = (kk & 1) ? __shfl(vhi, k >> 1) : __shfl(vlo, k >> 1);
        p = fmaf(xk, w3s[k * 16 + c], p);
    }
    p += __shfl_xor(p, 16);
    p += __shfl_xor(p, 32);
    if (lane < 16) g3[(size_t)node * 16 + c] = f2bf(p * dv);
}

// ==================== gather3: paired-bf16 F=16 gather + self + bias + log_softmax ====================

__global__ __launch_bounds__(256) void gather3(const int* __restrict__ csr_src,
        const int* __restrict__ start, const int* __restrict__ cnt,
        const unsigned short* __restrict__ g, const float* __restrict__ dis,
        const float* __restrict__ bias, float* __restrict__ out, int n) {
    int node = blockIdx.x * 4 + (threadIdx.x >> 6);
    if (node >= n) return;
    int lane = threadIdx.x & 63;
    int fpair = lane & 7;
    int j = lane >> 3;
    int i0 = start[node], i1 = i0 + cnt[node];
    float alo = 0.f, ahi = 0.f;
    int i = i0 + j;
    for (; i + 24 < i1; i += 32) {
        int s1 = csr_src[i];
        int s2 = csr_src[i + 8];
        int s3 = csr_src[i + 16];
        int s4 = csr_src[i + 24];
        unsigned v1 = *(const unsigned*)(g + (size_t)s1 * 16 + fpair * 2);
        unsigned v2 = *(const unsigned*)(g + (size_t)s2 * 16 + fpair * 2);
        unsigned v3 = *(const unsigned*)(g + (size_t)s3 * 16 + fpair * 2);
        unsigned v4 = *(const unsigned*)(g + (size_t)s4 * 16 + fpair * 2);
        alo += bflo(v1) + bflo(v2) + bflo(v3) + bflo(v4);
        ahi += bfhi(v1) + bfhi(v2) + bfhi(v3) + bfhi(v4);
    }
    for (; i < i1; i += 8) {
        unsigned v = *(const unsigned*)(g + (size_t)csr_src[i] * 16 + fpair * 2);
        alo += bflo(v); ahi += bfhi(v);
    }
    alo += __shfl_xor(alo, 8); alo += __shfl_xor(alo, 16); alo += __shfl_xor(alo, 32);
    ahi += __shfl_xor(ahi, 8); ahi += __shfl_xor(ahi, 16); ahi += __shfl_xor(ahi, 32);
    unsigned sv = *(const unsigned*)(g + (size_t)node * 16 + fpair * 2);
    float dvn = dis[node];
    int flo = 2 * fpair, fhi = 2 * fpair + 1;
    bool oklo = flo < 11, okhi = fhi < 11;
    float vlo = (alo + bflo(sv)) * dvn + (oklo ? bias[flo] : 0.f);
    float vhi = (ahi + bfhi(sv)) * dvn + (okhi ? bias[fhi] : 0.f);
    float m = fmaxf(oklo ? vlo : -3.0e38f, okhi ? vhi : -3.0e38f);
    m = fmaxf(m, __shfl_xor(m, 1));
    m = fmaxf(m, __shfl_xor(m, 2));
    m = fmaxf(m, __shfl_xor(m, 4));
    float s = (oklo ? __expf(vlo - m) : 0.f) + (okhi ? __expf(vhi - m) : 0.f);
    s += __shfl_xor(s, 1); s += __shfl_xor(s, 2); s += __shfl_xor(s, 4);
    float ls = __logf(s) + m;
    if (lane < 8) {
        if (oklo) out[(size_t)node * 11 + flo] = vlo - ls;
        if (okhi) out[(size_t)node * 11 + fhi] = vhi - ls;
    }
}

// ==================== launch ====================

extern "C" void kernel_launch(void* const* d_in, const int* in_sizes, int n_in,
                              void* d_out, int out_size, void* d_ws, size_t ws_size,
                              hipStream_t stream) {
    const float* x  = (const float*)d_in[0];
    const int*   ei = (const int*)d_in[1];
    const float* W1 = (const float*)d_in[2];
    const float* b1 = (const float*)d_in[3];
    const float* W2 = (const float*)d_in[4];
    const float* b2 = (const float*)d_in[5];
    const float* W3 = (const float*)d_in[6];
    const float* b3 = (const float*)d_in[7];
    float* out = (float*)d_out;

    const int n = in_sizes[0] / 512;
    const int E = in_sizes[1] / 2;
    const int* src = ei;
    const int* dst = ei + E;

    const int NB = (n + BKT_NODES - 1) >> BKT_SHIFT;      // 782
    const int B  = (E + CHUNK - 1) / CHUNK;               // 196
    const int NBB = NB * B;
    const int nb_scan = (NBB + SCAN_ELEMS - 1) / SCAN_ELEMS;

    // workspace layout (4B elements)
    int* ws0 = (int*)d_ws;
    size_t off = 0;
    int*   cnt     = ws0 + off; off += (size_t)n;
    float* dis     = (float*)(ws0 + off); off += (size_t)n;
    int*   nstart  = ws0 + off; off += (size_t)n;
    int*   scanG   = ws0 + off; off += (size_t)NBB;
    int*   blksum  = ws0 + off; off += 256;
    int*   pairs   = ws0 + off; off += (size_t)E;
    int*   csr_src = ws0 + off; off += (size_t)E;
    unsigned short* g1 = (unsigned short*)(ws0 + off); off += (size_t)n * 16;  // n*32 bf16
    unsigned short* g2 = (unsigned short*)(ws0 + off); off += (size_t)n * 8;   // n*16 bf16
    unsigned short* g3 = (unsigned short*)(ws0 + off); off += (size_t)n * 8;   // n*16 bf16
    unsigned short* W1T = (unsigned short*)(ws0 + off); off += 8192;           // 32x512 bf16
    int*   histG   = (int*)g1;  // alias: histG dead before gemm1 writes g1

    // ---- bucket binning + within-bucket counting sort -> dst-sorted CSR + deg/dis ----
    hist_k<<<B, 512, 0, stream>>>(dst, histG, B, NB, E);
    scan1<<<nb_scan, 256, 0, stream>>>(histG, scanG, blksum, NBB);
    scan2<<<1, 256, 0, stream>>>(blksum, nb_scan);
    wconv<<<64, 256, 0, stream>>>(W1, W1T);
    scatter_k<<<B, 512, 0, stream>>>(src, dst, scanG, blksum, pairs, B, NB, E);
    sort_bucket<<<NB, 512, 0, stream>>>(pairs, scanG, blksum, B, NB, csr_src, nstart, cnt, dis, n, E);

    // ---- layer 1 GEMM (MFMA), then fused gather chains ----
    gemm1_mfma<<<(n + 63) / 64, 256, 0, stream>>>(x, W1T, dis, g1, n);
    gather1<<<(n + 3) / 4, 256, 0, stream>>>(csr_src, nstart, cnt, g1, dis, b1, W2, g2, n);
    gather2<<<(n + 3) / 4, 256, 0, stream>>>(csr_src, nstart, cnt, g2, dis, b2, W3, g3, n);
    gather3<<<(n + 3) / 4, 256, 0, stream>>>(csr_src, nstart, cnt, g3, dis, b3, out, n);
}

// Round 15
// 286.084 us; speedup vs baseline: 1.3677x; 1.0170x over previous
//
#include <hip/hip_runtime.h>
#include <hip/hip_bf16.h>

// ---- bf16 helpers (manual, finite-value RNE) ----
static __device__ __forceinline__ unsigned short f2bf(float f) {
    unsigned u = __float_as_uint(f);
    unsigned r = (u + 0x7FFF + ((u >> 16) & 1)) >> 16;
    return (unsigned short)r;
}
static __device__ __forceinline__ float bflo(unsigned v) { return __uint_as_float(v << 16); }
static __device__ __forceinline__ float bfhi(unsigned v) { return __uint_as_float(v & 0xFFFF0000u); }
// packed 2xf32 -> 2xbf16 (RNE) via v_cvt_pk_bf16_f32; memory order: a low, b high
static __device__ __forceinline__ unsigned pack2bf(float a, float b) {
    __hip_bfloat162 h2 = __float22bfloat162_rn(float2{a, b});
    union { __hip_bfloat162 h; unsigned u; } cv;
    cv.h = h2;
    return cv.u;
}

typedef __attribute__((ext_vector_type(8))) short bf16x8;
typedef __attribute__((ext_vector_type(8))) unsigned short u16x8;
typedef __attribute__((ext_vector_type(4))) float f32x4;

// ==================== bucket binning ====================
#define BKT_SHIFT 7
#define BKT_NODES 128
#define CHUNK 16384  // edges per hist/scatter block (512 thr x 32) -> B=196 blocks

__global__ __launch_bounds__(512) void hist_k(const int* __restrict__ dst, int* __restrict__ histG,
                                              int B, int NB, int E) {
    __shared__ int hist[1024];
    int tid = threadIdx.x;
    for (int i = tid; i < NB; i += 512) hist[i] = 0;
    __syncthreads();
    int base = blockIdx.x * CHUNK;
    for (int i = tid; i < CHUNK; i += 512) {
        int e = base + i;
        if (e >= E) break;
        atomicAdd(&hist[dst[e] >> BKT_SHIFT], 1);
    }
    __syncthreads();
    for (int i = tid; i < NB; i += 512) histG[(size_t)i * B + blockIdx.x] = hist[i];
}

// scatter with scan3 folded in (adds blksum[idx>>11] on the fly)
__global__ __launch_bounds__(512) void scatter_k(const int* __restrict__ src, const int* __restrict__ dst,
                                                 const int* __restrict__ scanG, const int* __restrict__ blksum,
                                                 int* __restrict__ pairs, int B, int NB, int E) {
    __shared__ int sbase[1024];
    __shared__ int scnt[1024];
    int tid = threadIdx.x;
    for (int i = tid; i < NB; i += 512) {
        size_t idx = (size_t)i * B + blockIdx.x;
        sbase[i] = scanG[idx] + blksum[idx >> 11];
        scnt[i] = 0;
    }
    __syncthreads();
    int base = blockIdx.x * CHUNK;
    for (int i = tid; i < CHUNK; i += 512) {
        int e = base + i;
        if (e >= E) break;
        int d = dst[e], s = src[e];
        int b = d >> BKT_SHIFT;
        int r = atomicAdd(&scnt[b], 1);
        pairs[sbase[b] + r] = (s << BKT_SHIFT) | (d & (BKT_NODES - 1));
    }
}

// ==================== scan (exclusive), 256 thr x 8 = 2048 elems/block ====================
#define SCAN_VPT 8
#define SCAN_ELEMS 2048

__global__ __launch_bounds__(256) void scan1(const int* __restrict__ in, int* __restrict__ out,
                                             int* __restrict__ blksum, int n) {
    __shared__ int sh[256];
    int base = blockIdx.x * SCAN_ELEMS + threadIdx.x * SCAN_VPT;
    int v[SCAN_VPT];
    int sum = 0;
    #pragma unroll
    for (int j = 0; j < SCAN_VPT; ++j) {
        v[j] = (base + j < n) ? in[base + j] : 0;
        sum += v[j];
    }
    sh[threadIdx.x] = sum;
    __syncthreads();
    for (int off = 1; off < 256; off <<= 1) {
        int t = (threadIdx.x >= off) ? sh[threadIdx.x - off] : 0;
        __syncthreads();
        sh[threadIdx.x] += t;
        __syncthreads();
    }
    if (threadIdx.x == 255) blksum[blockIdx.x] = sh[255];
    int run = sh[threadIdx.x] - sum;
    #pragma unroll
    for (int j = 0; j < SCAN_VPT; ++j) {
        if (base + j < n) out[base + j] = run;
        run += v[j];
    }
}

__global__ __launch_bounds__(256) void scan2(int* __restrict__ blksum, int nb) {
    __shared__ int sh[256];
    int t = threadIdx.x;
    int v = (t < nb) ? blksum[t] : 0;
    sh[t] = v;
    __syncthreads();
    for (int off = 1; off < 256; off <<= 1) {
        int u = (t >= off) ? sh[t - off] : 0;
        __syncthreads();
        sh[t] += u;
        __syncthreads();
    }
    if (t < nb) blksum[t] = sh[t] - v;
}

// ==================== W1 -> bf16 transposed [32][512] (once) ====================
__global__ __launch_bounds__(256) void wconv(const float* __restrict__ W, unsigned short* __restrict__ W1T) {
    int gidx = blockIdx.x * 256 + threadIdx.x;  // 0..16383
    if (gidx < 32 * 512) {
        int c = gidx >> 9, k = gidx & 511;
        W1T[gidx] = f2bf(W[(size_t)k * 32 + c]);
    }
}

// ==================== within-bucket counting sort -> dst-sorted CSR + degree/dis ====================
#define SORT_CAP 8192

__global__ __launch_bounds__(512) void sort_bucket(const int* __restrict__ pairs,
        const int* __restrict__ scanG, const int* __restrict__ blksum, int B, int NB,
        int* __restrict__ csr_src, int* __restrict__ node_start,
        int* __restrict__ cnt, float* __restrict__ dis, int n, int E) {
    __shared__ int keys[SORT_CAP];
    __shared__ int lcnt[BKT_NODES];
    __shared__ int lscan[BKT_NODES];
    __shared__ int lfill[BKT_NODES];
    int bkt = blockIdx.x, tid = threadIdx.x;
    size_t idx0 = (size_t)bkt * B;
    int e0 = scanG[idx0] + blksum[idx0 >> 11];
    int e1 = E;
    if (bkt + 1 < NB) {
        size_t idx1 = (size_t)(bkt + 1) * B;
        e1 = scanG[idx1] + blksum[idx1 >> 11];
    }
    int m = e1 - e0;
    if (tid < BKT_NODES) { lcnt[tid] = 0; lfill[tid] = 0; }
    __syncthreads();
    for (int i = tid; i < m; i += 512) {
        int k = pairs[e0 + i];
        if (i < SORT_CAP) keys[i] = k;
        atomicAdd(&lcnt[k & (BKT_NODES - 1)], 1);
    }
    __syncthreads();
    // wave-0 parallel exclusive scan of lcnt[128] (2 elems/lane)
    if (tid < 64) {
        int c0 = lcnt[2 * tid], c1 = lcnt[2 * tid + 1];
        int s = c0 + c1;
        #pragma unroll
        for (int off = 1; off < 64; off <<= 1) {
            int t = __shfl_up(s, off);
            if (tid >= off) s += t;
        }
        lscan[2 * tid]     = s - c1 - c0;
        lscan[2 * tid + 1] = s - c1;
    }
    __syncthreads();
    int nb0 = bkt << BKT_SHIFT;
    if (tid < BKT_NODES && nb0 + tid < n) {
        int deg = lcnt[tid];
        node_start[nb0 + tid] = e0 + lscan[tid];
        cnt[nb0 + tid] = deg;
        dis[nb0 + tid] = rsqrtf((float)deg + 1.0f);
    }
    for (int i = tid; i < m; i += 512) {
        int k = (i < SORT_CAP) ? keys[i] : pairs[e0 + i];
        int d = k & (BKT_NODES - 1);
        int pos = lscan[d] + atomicAdd(&lfill[d], 1);
        csr_src[e0 + pos] = k >> BKT_SHIFT;
    }
}

// ==================== gemm1 (MFMA): 512->32 bf16, 64 nodes/block, x direct-to-register ====================
// Lane (mrow, kg) loads x[node][kg*8..+8] per 32-k step: lanes kg=0..3 of a row cover a
// contiguous 128B line (perfect coalescing). f32->bf16 in registers; no x LDS, no per-iter syncs.

__global__ __launch_bounds__(256) void gemm1_mfma(const float* __restrict__ x, const unsigned short* __restrict__ W1T,
                                                  const float* __restrict__ dis, unsigned short* __restrict__ g, int n) {
    __shared__ __attribute__((aligned(16))) unsigned short wT[32][520];  // [col][k], +8 pad
    int tid = threadIdx.x;
    int node0 = blockIdx.x * 64;

    // one-time: copy W1T bf16 into LDS (2048 ushort8 loads)
    #pragma unroll
    for (int r = 0; r < 8; ++r) {
        int u8 = tid + r * 256;            // ushort8 index 0..2047
        int c = u8 >> 6, kq = (u8 & 63) * 8;
        *(u16x8*)(&wT[c][kq]) = *(const u16x8*)(W1T + (size_t)c * 512 + kq);
    }

    int wv_ = tid >> 6;       // wave 0..3 -> node sub-tile
    int lane = tid & 63;
    int mrow = lane & 15;     // A row / B col / D col
    int kg = lane >> 4;       // k-group 0..3 (8 k each)
    int lnode = node0 + wv_ * 16 + mrow;
    int gn = min(lnode, n - 1);
    const float* xrow = x + (size_t)gn * 512 + kg * 8;
    f32x4 acc0 = {0.f, 0.f, 0.f, 0.f};
    f32x4 acc1 = {0.f, 0.f, 0.f, 0.f};
    __syncthreads();

    #pragma unroll 4
    for (int k0 = 0; k0 < 512; k0 += 32) {
        float4 xa = *(const float4*)(xrow + k0);
        float4 xc = *(const float4*)(xrow + k0 + 4);
        union { unsigned u[4]; bf16x8 v; } a;
        a.u[0] = pack2bf(xa.x, xa.y);
        a.u[1] = pack2bf(xa.z, xa.w);
        a.u[2] = pack2bf(xc.x, xc.y);
        a.u[3] = pack2bf(xc.z, xc.w);
        bf16x8 b0 = *(const bf16x8*)(&wT[mrow][k0 + kg * 8]);
        bf16x8 b1 = *(const bf16x8*)(&wT[16 + mrow][k0 + kg * 8]);
        acc0 = __builtin_amdgcn_mfma_f32_16x16x32_bf16(a.v, b0, acc0, 0, 0, 0);
        acc1 = __builtin_amdgcn_mfma_f32_16x16x32_bf16(a.v, b1, acc1, 0, 0, 0);
    }
    // D: col = lane&15 (=mrow), row = kg*4 + j
    #pragma unroll
    for (int j = 0; j < 4; ++j) {
        int node = node0 + wv_ * 16 + kg * 4 + j;
        if (node < n) {
            float dv = dis[node];
            g[(size_t)node * 32 + mrow]      = f2bf(acc0[j] * dv);
            g[(size_t)node * 32 + 16 + mrow] = f2bf(acc1[j] * dv);
        }
    }
}

// ==================== gather1: uint2 CSR gather F=32 + fused (relu -> @W2 -> *dis) ====================
// lane = (fq 0..7, j 0..7): 4 features/lane, 8 edges in flight per load instruction.

__global__ __launch_bounds__(256) void gather1(const int* __restrict__ csr_src,
        const int* __restrict__ start, const int* __restrict__ cnt,
        const unsigned short* __restrict__ g1, const float* __restrict__ dis,
        const float* __restrict__ b1, const float* __restrict__ W2,
        unsigned short* __restrict__ g2, int n) {
    __shared__ float w2t[16 * 33];  // transposed [c][k], stride 33 (conflict-free)
    for (int i = threadIdx.x; i < 512; i += 256) {
        int k = i >> 4, c = i & 15;
        w2t[c * 33 + k] = W2[i];
    }
    __syncthreads();
    int node = blockIdx.x * 4 + (threadIdx.x >> 6);
    if (node >= n) return;
    int lane = threadIdx.x & 63;
    int fq = lane & 7;           // features 4fq..4fq+3
    int j = lane >> 3;           // 0..7
    int i0 = start[node], i1 = i0 + cnt[node];
    float a0 = 0.f, a1 = 0.f, a2 = 0.f, a3 = 0.f;
    int i = i0 + j;
    for (; i + 24 < i1; i += 32) {
        int s1 = csr_src[i];
        int s2 = csr_src[i + 8];
        int s3 = csr_src[i + 16];
        int s4 = csr_src[i + 24];
        uint2 v1 = *(const uint2*)(g1 + (size_t)s1 * 32 + fq * 4);
        uint2 v2 = *(const uint2*)(g1 + (size_t)s2 * 32 + fq * 4);
        uint2 v3 = *(const uint2*)(g1 + (size_t)s3 * 32 + fq * 4);
        uint2 v4 = *(const uint2*)(g1 + (size_t)s4 * 32 + fq * 4);
        a0 += bflo(v1.x) + bflo(v2.x) + bflo(v3.x) + bflo(v4.x);
        a1 += bfhi(v1.x) + bfhi(v2.x) + bfhi(v3.x) + bfhi(v4.x);
        a2 += bflo(v1.y) + bflo(v2.y) + bflo(v3.y) + bflo(v4.y);
        a3 += bfhi(v1.y) + bfhi(v2.y) + bfhi(v3.y) + bfhi(v4.y);
    }
    for (; i < i1; i += 8) {
        uint2 v = *(const uint2*)(g1 + (size_t)csr_src[i] * 32 + fq * 4);
        a0 += bflo(v.x); a1 += bfhi(v.x);
        a2 += bflo(v.y); a3 += bfhi(v.y);
    }
    #pragma unroll
    for (int m = 8; m < 64; m <<= 1) {
        a0 += __shfl_xor(a0, m); a1 += __shfl_xor(a1, m);
        a2 += __shfl_xor(a2, m); a3 += __shfl_xor(a3, m);
    }
    float dv = dis[node];
    uint2 sv = *(const uint2*)(g1 + (size_t)node * 32 + fq * 4);
    float v0 = fmaxf((a0 + bflo(sv.x)) * dv + b1[4 * fq + 0], 0.f);
    float v1f = fmaxf((a1 + bfhi(sv.x)) * dv + b1[4 * fq + 1], 0.f);
    float v2f = fmaxf((a2 + bflo(sv.y)) * dv + b1[4 * fq + 2], 0.f);
    float v3f = fmaxf((a3 + bfhi(sv.y)) * dv + b1[4 * fq + 3], 0.f);
    // fused 32->16 projection: col c = lane&15; j3 = lane>>4 covers k = 8*j3..8*j3+7
    int c = lane & 15;
    int j3 = lane >> 4;
    float p = 0.f;
    #pragma unroll
    for (int kk = 0; kk < 8; ++kk) {
        int k = j3 * 8 + kk;
        int srcl = k >> 2;        // holder lane (0..7)
        float xk;
        if ((kk & 3) == 0) xk = __shfl(v0, srcl);
        else if ((kk & 3) == 1) xk = __shfl(v1f, srcl);
        else if ((kk & 3) == 2) xk = __shfl(v2f, srcl);
        else xk = __shfl(v3f, srcl);
        p = fmaf(xk, w2t[c * 33 + k], p);
    }
    p += __shfl_xor(p, 16);
    p += __shfl_xor(p, 32);
    if (lane < 16) g2[(size_t)node * 16 + c] = f2bf(p * dv);
}

// ==================== gather2: uint2 CSR gather F=16 + fused (relu -> @W3 -> *dis) ====================
// lane = (fq 0..3, j 0..15): 4 features/lane, 16 edges in flight per load instruction.

__global__ __launch_bounds__(256) void gather2(const int* __restrict__ csr_src,
        const int* __restrict__ start, const int* __restrict__ cnt,
        const unsigned short* __restrict__ g2, const float* __restrict__ dis,
        const float* __restrict__ b2, const float* __restrict__ W3,
        unsigned short* __restrict__ g3, int n) {
    __shared__ float w3t[16 * 17];  // transposed [c][k], stride 17, zero-padded cols 11..15
    if (threadIdx.x < 256) {
        int k = threadIdx.x >> 4, c = threadIdx.x & 15;
        w3t[c * 17 + k] = (c < 11) ? W3[(size_t)k * 11 + c] : 0.f;
    }
    __syncthreads();
    int node = blockIdx.x * 4 + (threadIdx.x >> 6);
    if (node >= n) return;
    int lane = threadIdx.x & 63;
    int fq = lane & 3;           // features 4fq..4fq+3
    int j = lane >> 2;           // 0..15
    int i0 = start[node], i1 = i0 + cnt[node];
    float a0 = 0.f, a1 = 0.f, a2 = 0.f, a3 = 0.f;
    int i = i0 + j;
    for (; i + 16 < i1; i += 32) {
        int s1 = csr_src[i];
        int s2 = csr_src[i + 16];
        uint2 v1 = *(const uint2*)(g2 + (size_t)s1 * 16 + fq * 4);
        uint2 v2 = *(const uint2*)(g2 + (size_t)s2 * 16 + fq * 4);
        a0 += bflo(v1.x) + bflo(v2.x);
        a1 += bfhi(v1.x) + bfhi(v2.x);
        a2 += bflo(v1.y) + bflo(v2.y);
        a3 += bfhi(v1.y) + bfhi(v2.y);
    }
    if (i < i1) {
        uint2 v = *(const uint2*)(g2 + (size_t)csr_src[i] * 16 + fq * 4);
        a0 += bflo(v.x); a1 += bfhi(v.x);
        a2 += bflo(v.y); a3 += bfhi(v.y);
    }
    #pragma unroll
    for (int m = 4; m < 64; m <<= 1) {
        a0 += __shfl_xor(a0, m); a1 += __shfl_xor(a1, m);
        a2 += __shfl_xor(a2, m); a3 += __shfl_xor(a3, m);
    }
    float dv = dis[node];
    uint2 sv = *(const uint2*)(g2 + (size_t)node * 16 + fq * 4);
    float v0 = fmaxf((a0 + bflo(sv.x)) * dv + b2[4 * fq + 0], 0.f);
    float v1f = fmaxf((a1 + bfhi(sv.x)) * dv + b2[4 * fq + 1], 0.f);
    float v2f = fmaxf((a2 + bflo(sv.y)) * dv + b2[4 * fq + 2], 0.f);
    float v3f = fmaxf((a3 + bfhi(sv.y)) * dv + b2[4 * fq + 3], 0.f);
    // fused 16->16(11 padded) projection: col c = lane&15; j2 = lane>>4 covers k = 4*j2..4*j2+3
    int c = lane & 15;
    int j2 = lane >> 4;
    float p = 0.f;
    {
        float xk0 = __shfl(v0, j2);
        float xk1 = __shfl(v1f, j2);
        float xk2 = __shfl(v2f, j2);
        float xk3 = __shfl(v3f, j2);
        p = fmaf(xk0, w3t[c * 17 + j2 * 4 + 0], p);
        p = fmaf(xk1, w3t[c * 17 + j2 * 4 + 1], p);
        p = fmaf(xk2, w3t[c * 17 + j2 * 4 + 2], p);
        p = fmaf(xk3, w3t[c * 17 + j2 * 4 + 3], p);
    }
    p += __shfl_xor(p, 16);
    p += __shfl_xor(p, 32);
    if (lane < 16) g3[(size_t)node * 16 + c] = f2bf(p * dv);
}

// ==================== gather3: uint2 F=16 gather + self + bias + log_softmax ====================

__global__ __launch_bounds__(256) void gather3(const int* __restrict__ csr_src,
        const int* __restrict__ start, const int* __restrict__ cnt,
        const unsigned short* __restrict__ g, const float* __restrict__ dis,
        const float* __restrict__ bias, float* __restrict__ out, int n) {
    int node = blockIdx.x * 4 + (threadIdx.x >> 6);
    if (node >= n) return;
    int lane = threadIdx.x & 63;
    int fq = lane & 3;
    int j = lane >> 2;
    int i0 = start[node], i1 = i0 + cnt[node];
    float a0 = 0.f, a1 = 0.f, a2 = 0.f, a3 = 0.f;
    int i = i0 + j;
    for (; i + 16 < i1; i += 32) {
        int s1 = csr_src[i];
        int s2 = csr_src[i + 16];
        uint2 v1 = *(const uint2*)(g + (size_t)s1 * 16 + fq * 4);
        uint2 v2 = *(const uint2*)(g + (size_t)s2 * 16 + fq * 4);
        a0 += bflo(v1.x) + bflo(v2.x);
        a1 += bfhi(v1.x) + bfhi(v2.x);
        a2 += bflo(v1.y) + bflo(v2.y);
        a3 += bfhi(v1.y) + bfhi(v2.y);
    }
    if (i < i1) {
        uint2 v = *(const uint2*)(g + (size_t)csr_src[i] * 16 + fq * 4);
        a0 += bflo(v.x); a1 += bfhi(v.x);
        a2 += bflo(v.y); a3 += bfhi(v.y);
    }
    #pragma unroll
    for (int m = 4; m < 64; m <<= 1) {
        a0 += __shfl_xor(a0, m); a1 += __shfl_xor(a1, m);
        a2 += __shfl_xor(a2, m); a3 += __shfl_xor(a3, m);
    }
    float dvn = dis[node];
    uint2 sv = *(const uint2*)(g + (size_t)node * 16 + fq * 4);
    int f0 = 4 * fq;
    bool ok0 = f0 + 0 < 11, ok1 = f0 + 1 < 11, ok2 = f0 + 2 < 11, ok3 = f0 + 3 < 11;
    float v0 = (a0 + bflo(sv.x)) * dvn + (ok0 ? bias[f0 + 0] : 0.f);
    float v1f = (a1 + bfhi(sv.x)) * dvn + (ok1 ? bias[f0 + 1] : 0.f);
    float v2f = (a2 + bflo(sv.y)) * dvn + (ok2 ? bias[f0 + 2] : 0.f);
    float v3f = (a3 + bfhi(sv.y)) * dvn + (ok3 ? bias[f0 + 3] : 0.f);
    const float NEG = -3.0e38f;
    float m0 = fmaxf(fmaxf(ok0 ? v0 : NEG, ok1 ? v1f : NEG),
                     fmaxf(ok2 ? v2f : NEG, ok3 ? v3f : NEG));
    m0 = fmaxf(m0, __shfl_xor(m0, 1));
    m0 = fmaxf(m0, __shfl_xor(m0, 2));
    float s = (ok0 ? __expf(v0 - m0) : 0.f) + (ok1 ? __expf(v1f - m0) : 0.f)
            + (ok2 ? __expf(v2f - m0) : 0.f) + (ok3 ? __expf(v3f - m0) : 0.f);
    s += __shfl_xor(s, 1);
    s += __shfl_xor(s, 2);
    float ls = __logf(s) + m0;
    if (lane < 4) {
        float* orow = out + (size_t)node * 11 + f0;
        if (ok0) orow[0] = v0 - ls;
        if (ok1) orow[1] = v1f - ls;
        if (ok2) orow[2] = v2f - ls;
        if (ok3) orow[3] = v3f - ls;
    }
}

// ==================== launch ====================

extern "C" void kernel_launch(void* const* d_in, const int* in_sizes, int n_in,
                              void* d_out, int out_size, void* d_ws, size_t ws_size,
                              hipStream_t stream) {
    const float* x  = (const float*)d_in[0];
    const int*   ei = (const int*)d_in[1];
    const float* W1 = (const float*)d_in[2];
    const float* b1 = (const float*)d_in[3];
    const float* W2 = (const float*)d_in[4];
    const float* b2 = (const float*)d_in[5];
    const float* W3 = (const float*)d_in[6];
    const float* b3 = (const float*)d_in[7];
    float* out = (float*)d_out;

    const int n = in_sizes[0] / 512;
    const int E = in_sizes[1] / 2;
    const int* src = ei;
    const int* dst = ei + E;

    const int NB = (n + BKT_NODES - 1) >> BKT_SHIFT;      // 782
    const int B  = (E + CHUNK - 1) / CHUNK;               // 196
    const int NBB = NB * B;
    const int nb_scan = (NBB + SCAN_ELEMS - 1) / SCAN_ELEMS;

    // workspace layout (4B elements)
    int* ws0 = (int*)d_ws;
    size_t off = 0;
    int*   cnt     = ws0 + off; off += (size_t)n;
    float* dis     = (float*)(ws0 + off); off += (size_t)n;
    int*   nstart  = ws0 + off; off += (size_t)n;
    int*   scanG   = ws0 + off; off += (size_t)NBB;
    int*   blksum  = ws0 + off; off += 256;
    int*   pairs   = ws0 + off; off += (size_t)E;
    int*   csr_src = ws0 + off; off += (size_t)E;
    unsigned short* g1 = (unsigned short*)(ws0 + off); off += (size_t)n * 16;  // n*32 bf16
    unsigned short* g2 = (unsigned short*)(ws0 + off); off += (size_t)n * 8;   // n*16 bf16
    unsigned short* g3 = (unsigned short*)(ws0 + off); off += (size_t)n * 8;   // n*16 bf16
    unsigned short* W1T = (unsigned short*)(ws0 + off); off += 8192;           // 32x512 bf16
    int*   histG   = (int*)g1;  // alias: histG dead before gemm1 writes g1

    // ---- bucket binning + within-bucket counting sort -> dst-sorted CSR + deg/dis ----
    hist_k<<<B, 512, 0, stream>>>(dst, histG, B, NB, E);
    scan1<<<nb_scan, 256, 0, stream>>>(histG, scanG, blksum, NBB);
    scan2<<<1, 256, 0, stream>>>(blksum, nb_scan);
    wconv<<<64, 256, 0, stream>>>(W1, W1T);
    scatter_k<<<B, 512, 0, stream>>>(src, dst, scanG, blksum, pairs, B, NB, E);
    sort_bucket<<<NB, 512, 0, stream>>>(pairs, scanG, blksum, B, NB, csr_src, nstart, cnt, dis, n, E);

    // ---- layer 1 GEMM (MFMA, x direct-to-register), then fused gather chains ----
    gemm1_mfma<<<(n + 63) / 64, 256, 0, stream>>>(x, W1T, dis, g1, n);
    gather1<<<(n + 3) / 4, 256, 0, stream>>>(csr_src, nstart, cnt, g1, dis, b1, W2, g2, n);
    gather2<<<(n + 3) / 4, 256, 0, stream>>>(csr_src, nstart, cnt, g2, dis, b2, W3, g3, n);
    gather3<<<(n + 3) / 4, 256, 0, stream>>>(csr_src, nstart, cnt, g3, dis, b3, out, n);
}

// Round 16
// 282.078 us; speedup vs baseline: 1.3871x; 1.0142x over previous
//
#include <hip/hip_runtime.h>
#include <hip/hip_bf16.h>

// ---- bf16 helpers (manual, finite-value RNE) ----
static __device__ __forceinline__ unsigned short f2bf(float f) {
    unsigned u = __float_as_uint(f);
    unsigned r = (u + 0x7FFF + ((u >> 16) & 1)) >> 16;
    return (unsigned short)r;
}
static __device__ __forceinline__ float bflo(unsigned v) { return __uint_as_float(v << 16); }
static __device__ __forceinline__ float bfhi(unsigned v) { return __uint_as_float(v & 0xFFFF0000u); }
// packed 2xf32 -> 2xbf16 (RNE) via v_cvt_pk_bf16_f32; memory order: a low, b high
static __device__ __forceinline__ unsigned pack2bf(float a, float b) {
    __hip_bfloat162 h2 = __float22bfloat162_rn(float2{a, b});
    union { __hip_bfloat162 h; unsigned u; } cv;
    cv.h = h2;
    return cv.u;
}

typedef __attribute__((ext_vector_type(8))) short bf16x8;
typedef __attribute__((ext_vector_type(8))) unsigned short u16x8;
typedef __attribute__((ext_vector_type(4))) float f32x4;

// ==================== bucket binning ====================
#define BKT_SHIFT 7
#define BKT_NODES 128
#define CHUNK 16384  // edges per hist/scatter block (512 thr x 32) -> B=196 blocks

// hist (blocks < B) + W1 bf16-transpose conversion (blocks >= B)
__global__ __launch_bounds__(512) void hist_wconv(const int* __restrict__ dst, int* __restrict__ histG,
                                                  const float* __restrict__ W, unsigned short* __restrict__ W1T,
                                                  int B, int NB, int E) {
    if ((int)blockIdx.x >= B) {
        int gidx = (blockIdx.x - B) * 512 + threadIdx.x;  // 0..16383
        if (gidx < 32 * 512) {
            int c = gidx >> 9, k = gidx & 511;
            W1T[gidx] = f2bf(W[(size_t)k * 32 + c]);
        }
        return;
    }
    __shared__ int hist[1024];
    int tid = threadIdx.x;
    for (int i = tid; i < NB; i += 512) hist[i] = 0;
    __syncthreads();
    int base = blockIdx.x * CHUNK;
    for (int i = tid; i < CHUNK; i += 512) {
        int e = base + i;
        if (e >= E) break;
        atomicAdd(&hist[dst[e] >> BKT_SHIFT], 1);
    }
    __syncthreads();
    for (int i = tid; i < NB; i += 512) histG[(size_t)i * B + blockIdx.x] = hist[i];
}

// ==================== scan (exclusive), 256 thr x 8 = 2048 elems/block ====================
#define SCAN_VPT 8
#define SCAN_ELEMS 2048

__global__ __launch_bounds__(256) void scan1(const int* __restrict__ in, int* __restrict__ out,
                                             int* __restrict__ blksum, int n) {
    __shared__ int sh[256];
    int base = blockIdx.x * SCAN_ELEMS + threadIdx.x * SCAN_VPT;
    int v[SCAN_VPT];
    int sum = 0;
    #pragma unroll
    for (int j = 0; j < SCAN_VPT; ++j) {
        v[j] = (base + j < n) ? in[base + j] : 0;
        sum += v[j];
    }
    sh[threadIdx.x] = sum;
    __syncthreads();
    for (int off = 1; off < 256; off <<= 1) {
        int t = (threadIdx.x >= off) ? sh[threadIdx.x - off] : 0;
        __syncthreads();
        sh[threadIdx.x] += t;
        __syncthreads();
    }
    if (threadIdx.x == 255) blksum[blockIdx.x] = sh[255];
    int run = sh[threadIdx.x] - sum;
    #pragma unroll
    for (int j = 0; j < SCAN_VPT; ++j) {
        if (base + j < n) out[base + j] = run;
        run += v[j];
    }
}

__global__ __launch_bounds__(256) void scan2(int* __restrict__ blksum, int nb) {
    __shared__ int sh[256];
    int t = threadIdx.x;
    int v = (t < nb) ? blksum[t] : 0;
    sh[t] = v;
    __syncthreads();
    for (int off = 1; off < 256; off <<= 1) {
        int u = (t >= off) ? sh[t - off] : 0;
        __syncthreads();
        sh[t] += u;
        __syncthreads();
    }
    if (t < nb) blksum[t] = sh[t] - v;
}

// ==================== scatter (blocks < B) + gemm1 MFMA unscaled (blocks >= B) ====================
// gemm part: 128 nodes/block, 8 waves; lane (mrow,kg) streams x[node] from global,
// f32->bf16 in regs, MFMA vs LDS-staged W1T. Writes UNSCALED bf16 xW1 (dis applied later).

__global__ __launch_bounds__(512) void scatter_gemm(const int* __restrict__ src, const int* __restrict__ dst,
                                                    const int* __restrict__ scanG, const int* __restrict__ blksum,
                                                    int* __restrict__ pairs,
                                                    const float* __restrict__ x, const unsigned short* __restrict__ W1T,
                                                    unsigned short* __restrict__ g1,
                                                    int B, int NB, int E, int n) {
    __shared__ __attribute__((aligned(16))) unsigned char lds_raw[32 * 520 * 2];  // 33280 B
    int tid = threadIdx.x;

    if ((int)blockIdx.x < B) {
        // ---- scatter branch (scan3 folded in) ----
        int* sbase = (int*)lds_raw;            // NB ints
        int* scnt  = (int*)(lds_raw + 4096);   // NB ints
        for (int i = tid; i < NB; i += 512) {
            size_t idx = (size_t)i * B + blockIdx.x;
            sbase[i] = scanG[idx] + blksum[idx >> 11];
            scnt[i] = 0;
        }
        __syncthreads();
        int base = blockIdx.x * CHUNK;
        for (int i = tid; i < CHUNK; i += 512) {
            int e = base + i;
            if (e >= E) break;
            int d = dst[e], s = src[e];
            int b = d >> BKT_SHIFT;
            int r = atomicAdd(&scnt[b], 1);
            pairs[sbase[b] + r] = (s << BKT_SHIFT) | (d & (BKT_NODES - 1));
        }
        return;
    }

    // ---- gemm branch ----
    typedef unsigned short wrow_t[520];
    wrow_t* wT = (wrow_t*)lds_raw;             // [32][520]
    int bid = blockIdx.x - B;
    int node0 = bid * 128;

    #pragma unroll
    for (int r = 0; r < 4; ++r) {
        int u8 = tid + r * 512;                // ushort8 index 0..2047
        int c = u8 >> 6, kq = (u8 & 63) * 8;
        *(u16x8*)(&wT[c][kq]) = *(const u16x8*)(W1T + (size_t)c * 512 + kq);
    }

    int wv_ = tid >> 6;       // wave 0..7 -> 16-node sub-tile
    int lane = tid & 63;
    int mrow = lane & 15;     // A row / B col / D col
    int kg = lane >> 4;       // k-group 0..3 (8 k each)
    int lnode = node0 + wv_ * 16 + mrow;
    int gn = min(lnode, n - 1);
    const float* xrow = x + (size_t)gn * 512 + kg * 8;
    f32x4 acc0 = {0.f, 0.f, 0.f, 0.f};
    f32x4 acc1 = {0.f, 0.f, 0.f, 0.f};
    __syncthreads();

    #pragma unroll 4
    for (int k0 = 0; k0 < 512; k0 += 32) {
        float4 xa = *(const float4*)(xrow + k0);
        float4 xc = *(const float4*)(xrow + k0 + 4);
        union { unsigned u[4]; bf16x8 v; } a;
        a.u[0] = pack2bf(xa.x, xa.y);
        a.u[1] = pack2bf(xa.z, xa.w);
        a.u[2] = pack2bf(xc.x, xc.y);
        a.u[3] = pack2bf(xc.z, xc.w);
        bf16x8 b0 = *(const bf16x8*)(&wT[mrow][k0 + kg * 8]);
        bf16x8 b1 = *(const bf16x8*)(&wT[16 + mrow][k0 + kg * 8]);
        acc0 = __builtin_amdgcn_mfma_f32_16x16x32_bf16(a.v, b0, acc0, 0, 0, 0);
        acc1 = __builtin_amdgcn_mfma_f32_16x16x32_bf16(a.v, b1, acc1, 0, 0, 0);
    }
    // D: col = lane&15 (=mrow), row = kg*4 + j ; UNSCALED write
    #pragma unroll
    for (int j = 0; j < 4; ++j) {
        int node = node0 + wv_ * 16 + kg * 4 + j;
        if (node < n) {
            g1[(size_t)node * 32 + mrow]      = f2bf(acc0[j]);
            g1[(size_t)node * 32 + 16 + mrow] = f2bf(acc1[j]);
        }
    }
}

// ==================== within-bucket counting sort -> CSR + deg/dis + g1 scale epilogue ====================
#define SORT_CAP 8192

__global__ __launch_bounds__(512) void sort_bucket(const int* __restrict__ pairs,
        const int* __restrict__ scanG, const int* __restrict__ blksum, int B, int NB,
        int* __restrict__ csr_src, int* __restrict__ node_start,
        int* __restrict__ cnt, float* __restrict__ dis,
        unsigned short* __restrict__ g1, int n, int E) {
    __shared__ int keys[SORT_CAP];
    __shared__ int lcnt[BKT_NODES];
    __shared__ int lscan[BKT_NODES];
    __shared__ int lfill[BKT_NODES];
    __shared__ float sdis[BKT_NODES];
    int bkt = blockIdx.x, tid = threadIdx.x;
    size_t idx0 = (size_t)bkt * B;
    int e0 = scanG[idx0] + blksum[idx0 >> 11];
    int e1 = E;
    if (bkt + 1 < NB) {
        size_t idx1 = (size_t)(bkt + 1) * B;
        e1 = scanG[idx1] + blksum[idx1 >> 11];
    }
    int m = e1 - e0;
    if (tid < BKT_NODES) { lcnt[tid] = 0; lfill[tid] = 0; }
    __syncthreads();
    for (int i = tid; i < m; i += 512) {
        int k = pairs[e0 + i];
        if (i < SORT_CAP) keys[i] = k;
        atomicAdd(&lcnt[k & (BKT_NODES - 1)], 1);
    }
    __syncthreads();
    // wave-0 parallel exclusive scan of lcnt[128] (2 elems/lane)
    if (tid < 64) {
        int c0 = lcnt[2 * tid], c1 = lcnt[2 * tid + 1];
        int s = c0 + c1;
        #pragma unroll
        for (int off = 1; off < 64; off <<= 1) {
            int t = __shfl_up(s, off);
            if (tid >= off) s += t;
        }
        lscan[2 * tid]     = s - c1 - c0;
        lscan[2 * tid + 1] = s - c1;
    }
    __syncthreads();
    int nb0 = bkt << BKT_SHIFT;
    if (tid < BKT_NODES) {
        int deg = lcnt[tid];
        float d = rsqrtf((float)deg + 1.0f);
        sdis[tid] = d;
        if (nb0 + tid < n) {
            node_start[nb0 + tid] = e0 + lscan[tid];
            cnt[nb0 + tid] = deg;
            dis[nb0 + tid] = d;
        }
    }
    for (int i = tid; i < m; i += 512) {
        int k = (i < SORT_CAP) ? keys[i] : pairs[e0 + i];
        int d = k & (BKT_NODES - 1);
        int pos = lscan[d] + atomicAdd(&lfill[d], 1);
        csr_src[e0 + pos] = k >> BKT_SHIFT;
    }
    // ---- epilogue: scale this bucket's g1 rows by dis (g1 was written unscaled) ----
    __syncthreads();
    for (int i = tid; i < 1024; i += 512) {       // 1024 uint2 = 128 rows x 32 bf16
        int row = i >> 3;
        int node = nb0 + row;
        if (node >= n) break;
        float dvv = sdis[row];
        unsigned short* rp = g1 + (size_t)node * 32 + (i & 7) * 4;
        uint2 v = *(uint2*)rp;
        v.x = pack2bf(bflo(v.x) * dvv, bfhi(v.x) * dvv);
        v.y = pack2bf(bflo(v.y) * dvv, bfhi(v.y) * dvv);
        *(uint2*)rp = v;
    }
}

// ==================== gather1: uint2 CSR gather F=32 + fused (relu -> @W2 -> *dis) ====================

__global__ __launch_bounds__(256) void gather1(const int* __restrict__ csr_src,
        const int* __restrict__ start, const int* __restrict__ cnt,
        const unsigned short* __restrict__ g1, const float* __restrict__ dis,
        const float* __restrict__ b1, const float* __restrict__ W2,
        unsigned short* __restrict__ g2, int n) {
    __shared__ float w2t[16 * 33];  // transposed [c][k], stride 33 (conflict-free)
    for (int i = threadIdx.x; i < 512; i += 256) {
        int k = i >> 4, c = i & 15;
        w2t[c * 33 + k] = W2[i];
    }
    __syncthreads();
    int node = blockIdx.x * 4 + (threadIdx.x >> 6);
    if (node >= n) return;
    int lane = threadIdx.x & 63;
    int fq = lane & 7;           // features 4fq..4fq+3
    int j = lane >> 3;           // 0..7
    int i0 = start[node], i1 = i0 + cnt[node];
    float a0 = 0.f, a1 = 0.f, a2 = 0.f, a3 = 0.f;
    int i = i0 + j;
    for (; i + 24 < i1; i += 32) {
        int s1 = csr_src[i];
        int s2 = csr_src[i + 8];
        int s3 = csr_src[i + 16];
        int s4 = csr_src[i + 24];
        uint2 v1 = *(const uint2*)(g1 + (size_t)s1 * 32 + fq * 4);
        uint2 v2 = *(const uint2*)(g1 + (size_t)s2 * 32 + fq * 4);
        uint2 v3 = *(const uint2*)(g1 + (size_t)s3 * 32 + fq * 4);
        uint2 v4 = *(const uint2*)(g1 + (size_t)s4 * 32 + fq * 4);
        a0 += bflo(v1.x) + bflo(v2.x) + bflo(v3.x) + bflo(v4.x);
        a1 += bfhi(v1.x) + bfhi(v2.x) + bfhi(v3.x) + bfhi(v4.x);
        a2 += bflo(v1.y) + bflo(v2.y) + bflo(v3.y) + bflo(v4.y);
        a3 += bfhi(v1.y) + bfhi(v2.y) + bfhi(v3.y) + bfhi(v4.y);
    }
    for (; i < i1; i += 8) {
        uint2 v = *(const uint2*)(g1 + (size_t)csr_src[i] * 32 + fq * 4);
        a0 += bflo(v.x); a1 += bfhi(v.x);
        a2 += bflo(v.y); a3 += bfhi(v.y);
    }
    #pragma unroll
    for (int m = 8; m < 64; m <<= 1) {
        a0 += __shfl_xor(a0, m); a1 += __shfl_xor(a1, m);
        a2 += __shfl_xor(a2, m); a3 += __shfl_xor(a3, m);
    }
    float dv = dis[node];
    uint2 sv = *(const uint2*)(g1 + (size_t)node * 32 + fq * 4);
    float v0 = fmaxf((a0 + bflo(sv.x)) * dv + b1[4 * fq + 0], 0.f);
    float v1f = fmaxf((a1 + bfhi(sv.x)) * dv + b1[4 * fq + 1], 0.f);
    float v2f = fmaxf((a2 + bflo(sv.y)) * dv + b1[4 * fq + 2], 0.f);
    float v3f = fmaxf((a3 + bfhi(sv.y)) * dv + b1[4 * fq + 3], 0.f);
    // fused 32->16 projection: col c = lane&15; j3 = lane>>4 covers k = 8*j3..8*j3+7
    int c = lane & 15;
    int j3 = lane >> 4;
    float p = 0.f;
    #pragma unroll
    for (int kk = 0; kk < 8; ++kk) {
        int k = j3 * 8 + kk;
        int srcl = k >> 2;        // holder lane (0..7)
        float xk;
        if ((kk & 3) == 0) xk = __shfl(v0, srcl);
        else if ((kk & 3) == 1) xk = __shfl(v1f, srcl);
        else if ((kk & 3) == 2) xk = __shfl(v2f, srcl);
        else xk = __shfl(v3f, srcl);
        p = fmaf(xk, w2t[c * 33 + k], p);
    }
    p += __shfl_xor(p, 16);
    p += __shfl_xor(p, 32);
    if (lane < 16) g2[(size_t)node * 16 + c] = f2bf(p * dv);
}

// ==================== gather2: uint2 CSR gather F=16 + fused (relu -> @W3 -> *dis) ====================

__global__ __launch_bounds__(256) void gather2(const int* __restrict__ csr_src,
        const int* __restrict__ start, const int* __restrict__ cnt,
        const unsigned short* __restrict__ g2, const float* __restrict__ dis,
        const float* __restrict__ b2, const float* __restrict__ W3,
        unsigned short* __restrict__ g3, int n) {
    __shared__ float w3t[16 * 17];  // transposed [c][k], stride 17, zero-padded cols 11..15
    if (threadIdx.x < 256) {
        int k = threadIdx.x >> 4, c = threadIdx.x & 15;
        w3t[c * 17 + k] = (c < 11) ? W3[(size_t)k * 11 + c] : 0.f;
    }
    __syncthreads();
    int node = blockIdx.x * 4 + (threadIdx.x >> 6);
    if (node >= n) return;
    int lane = threadIdx.x & 63;
    int fq = lane & 3;           // features 4fq..4fq+3
    int j = lane >> 2;           // 0..15
    int i0 = start[node], i1 = i0 + cnt[node];
    float a0 = 0.f, a1 = 0.f, a2 = 0.f, a3 = 0.f;
    int i = i0 + j;
    for (; i + 16 < i1; i += 32) {
        int s1 = csr_src[i];
        int s2 = csr_src[i + 16];
        uint2 v1 = *(const uint2*)(g2 + (size_t)s1 * 16 + fq * 4);
        uint2 v2 = *(const uint2*)(g2 + (size_t)s2 * 16 + fq * 4);
        a0 += bflo(v1.x) + bflo(v2.x);
        a1 += bfhi(v1.x) + bfhi(v2.x);
        a2 += bflo(v1.y) + bflo(v2.y);
        a3 += bfhi(v1.y) + bfhi(v2.y);
    }
    if (i < i1) {
        uint2 v = *(const uint2*)(g2 + (size_t)csr_src[i] * 16 + fq * 4);
        a0 += bflo(v.x); a1 += bfhi(v.x);
        a2 += bflo(v.y); a3 += bfhi(v.y);
    }
    #pragma unroll
    for (int m = 4; m < 64; m <<= 1) {
        a0 += __shfl_xor(a0, m); a1 += __shfl_xor(a1, m);
        a2 += __shfl_xor(a2, m); a3 += __shfl_xor(a3, m);
    }
    float dv = dis[node];
    uint2 sv = *(const uint2*)(g2 + (size_t)node * 16 + fq * 4);
    float v0 = fmaxf((a0 + bflo(sv.x)) * dv + b2[4 * fq + 0], 0.f);
    float v1f = fmaxf((a1 + bfhi(sv.x)) * dv + b2[4 * fq + 1], 0.f);
    float v2f = fmaxf((a2 + bflo(sv.y)) * dv + b2[4 * fq + 2], 0.f);
    float v3f = fmaxf((a3 + bfhi(sv.y)) * dv + b2[4 * fq + 3], 0.f);
    // fused 16->16(11 padded) projection: col c = lane&15; j2 = lane>>4 covers k = 4*j2..4*j2+3
    int c = lane & 15;
    int j2 = lane >> 4;
    float p = 0.f;
    {
        float xk0 = __shfl(v0, j2);
        float xk1 = __shfl(v1f, j2);
        float xk2 = __shfl(v2f, j2);
        float xk3 = __shfl(v3f, j2);
        p = fmaf(xk0, w3t[c * 17 + j2 * 4 + 0], p);
        p = fmaf(xk1, w3t[c * 17 + j2 * 4 + 1], p);
        p = fmaf(xk2, w3t[c * 17 + j2 * 4 + 2], p);
        p = fmaf(xk3, w3t[c * 17 + j2 * 4 + 3], p);
    }
    p += __shfl_xor(p, 16);
    p += __shfl_xor(p, 32);
    if (lane < 16) g3[(size_t)node * 16 + c] = f2bf(p * dv);
}

// ==================== gather3: uint2 F=16 gather + self + bias + log_softmax ====================

__global__ __launch_bounds__(256) void gather3(const int* __restrict__ csr_src,
        const int* __restrict__ start, const int* __restrict__ cnt,
        const unsigned short* __restrict__ g, const float* __restrict__ dis,
        const float* __restrict__ bias, float* __restrict__ out, int n) {
    int node = blockIdx.x * 4 + (threadIdx.x >> 6);
    if (node >= n) return;
    int lane = threadIdx.x & 63;
    int fq = lane & 3;
    int j = lane >> 2;
    int i0 = start[node], i1 = i0 + cnt[node];
    float a0 = 0.f, a1 = 0.f, a2 = 0.f, a3 = 0.f;
    int i = i0 + j;
    for (; i + 16 < i1; i += 32) {
        int s1 = csr_src[i];
        int s2 = csr_src[i + 16];
        uint2 v1 = *(const uint2*)(g + (size_t)s1 * 16 + fq * 4);
        uint2 v2 = *(const uint2*)(g + (size_t)s2 * 16 + fq * 4);
        a0 += bflo(v1.x) + bflo(v2.x);
        a1 += bfhi(v1.x) + bfhi(v2.x);
        a2 += bflo(v1.y) + bflo(v2.y);
        a3 += bfhi(v1.y) + bfhi(v2.y);
    }
    if (i < i1) {
        uint2 v = *(const uint2*)(g + (size_t)csr_src[i] * 16 + fq * 4);
        a0 += bflo(v.x); a1 += bfhi(v.x);
        a2 += bflo(v.y); a3 += bfhi(v.y);
    }
    #pragma unroll
    for (int m = 4; m < 64; m <<= 1) {
        a0 += __shfl_xor(a0, m); a1 += __shfl_xor(a1, m);
        a2 += __shfl_xor(a2, m); a3 += __shfl_xor(a3, m);
    }
    float dvn = dis[node];
    uint2 sv = *(const uint2*)(g + (size_t)node * 16 + fq * 4);
    int f0 = 4 * fq;
    bool ok0 = f0 + 0 < 11, ok1 = f0 + 1 < 11, ok2 = f0 + 2 < 11, ok3 = f0 + 3 < 11;
    float v0 = (a0 + bflo(sv.x)) * dvn + (ok0 ? bias[f0 + 0] : 0.f);
    float v1f = (a1 + bfhi(sv.x)) * dvn + (ok1 ? bias[f0 + 1] : 0.f);
    float v2f = (a2 + bflo(sv.y)) * dvn + (ok2 ? bias[f0 + 2] : 0.f);
    float v3f = (a3 + bfhi(sv.y)) * dvn + (ok3 ? bias[f0 + 3] : 0.f);
    const float NEG = -3.0e38f;
    float m0 = fmaxf(fmaxf(ok0 ? v0 : NEG, ok1 ? v1f : NEG),
                     fmaxf(ok2 ? v2f : NEG, ok3 ? v3f : NEG));
    m0 = fmaxf(m0, __shfl_xor(m0, 1));
    m0 = fmaxf(m0, __shfl_xor(m0, 2));
    float s = (ok0 ? __expf(v0 - m0) : 0.f) + (ok1 ? __expf(v1f - m0) : 0.f)
            + (ok2 ? __expf(v2f - m0) : 0.f) + (ok3 ? __expf(v3f - m0) : 0.f);
    s += __shfl_xor(s, 1);
    s += __shfl_xor(s, 2);
    float ls = __logf(s) + m0;
    if (lane < 4) {
        float* orow = out + (size_t)node * 11 + f0;
        if (ok0) orow[0] = v0 - ls;
        if (ok1) orow[1] = v1f - ls;
        if (ok2) orow[2] = v2f - ls;
        if (ok3) orow[3] = v3f - ls;
    }
}

// ==================== launch ====================

extern "C" void kernel_launch(void* const* d_in, const int* in_sizes, int n_in,
                              void* d_out, int out_size, void* d_ws, size_t ws_size,
                              hipStream_t stream) {
    const float* x  = (const float*)d_in[0];
    const int*   ei = (const int*)d_in[1];
    const float* W1 = (const float*)d_in[2];
    const float* b1 = (const float*)d_in[3];
    const float* W2 = (const float*)d_in[4];
    const float* b2 = (const float*)d_in[5];
    const float* W3 = (const float*)d_in[6];
    const float* b3 = (const float*)d_in[7];
    float* out = (float*)d_out;

    const int n = in_sizes[0] / 512;
    const int E = in_sizes[1] / 2;
    const int* src = ei;
    const int* dst = ei + E;

    const int NB = (n + BKT_NODES - 1) >> BKT_SHIFT;      // 782
    const int B  = (E + CHUNK - 1) / CHUNK;               // 196
    const int NBB = NB * B;
    const int nb_scan = (NBB + SCAN_ELEMS - 1) / SCAN_ELEMS;

    // workspace layout (4B elements)
    int* ws0 = (int*)d_ws;
    size_t off = 0;
    int*   cnt     = ws0 + off; off += (size_t)n;
    float* dis     = (float*)(ws0 + off); off += (size_t)n;
    int*   nstart  = ws0 + off; off += (size_t)n;
    int*   scanG   = ws0 + off; off += (size_t)NBB;
    int*   blksum  = ws0 + off; off += 256;
    int*   pairs   = ws0 + off; off += (size_t)E;
    int*   csr_src = ws0 + off; off += (size_t)E;
    unsigned short* g1 = (unsigned short*)(ws0 + off); off += (size_t)n * 16;  // n*32 bf16
    unsigned short* g2 = (unsigned short*)(ws0 + off); off += (size_t)n * 8;   // n*16 bf16
    unsigned short* g3 = (unsigned short*)(ws0 + off); off += (size_t)n * 8;   // n*16 bf16
    unsigned short* W1T = (unsigned short*)(ws0 + off); off += 8192;           // 32x512 bf16
    int*   histG   = (int*)g1;  // alias: histG dead before scatter_gemm writes g1

    // ---- binning + W conv + gemm (fused/overlapped) ----
    hist_wconv<<<B + 32, 512, 0, stream>>>(dst, histG, W1, W1T, B, NB, E);
    scan1<<<nb_scan, 256, 0, stream>>>(histG, scanG, blksum, NBB);
    scan2<<<1, 256, 0, stream>>>(blksum, nb_scan);
    scatter_gemm<<<B + (n + 127) / 128, 512, 0, stream>>>(src, dst, scanG, blksum, pairs,
                                                          x, W1T, g1, B, NB, E, n);
    sort_bucket<<<NB, 512, 0, stream>>>(pairs, scanG, blksum, B, NB, csr_src, nstart, cnt, dis, g1, n, E);

    // ---- fused gather chains ----
    gather1<<<(n + 3) / 4, 256, 0, stream>>>(csr_src, nstart, cnt, g1, dis, b1, W2, g2, n);
    gather2<<<(n + 3) / 4, 256, 0, stream>>>(csr_src, nstart, cnt, g2, dis, b2, W3, g3, n);
    gather3<<<(n + 3) / 4, 256, 0, stream>>>(csr_src, nstart, cnt, g3, dis, b3, out, n);
}